// Round 4
// baseline (358.008 us; speedup 1.0000x reference)
//
#include <hip/hip_runtime.h>
#include <cmath>
#include <cstdint>

typedef __bf16 bf16;
typedef __bf16 bf16x8 __attribute__((ext_vector_type(8)));
typedef __bf16 bf16x4 __attribute__((ext_vector_type(4)));
typedef float  f32x4  __attribute__((ext_vector_type(4)));

#define M_TOK 8192
#define SCALE_ 0.10206207261596575f   // 96^-0.5

__device__ __forceinline__ void gld_lds16(const void* g, void* l) {
  __builtin_amdgcn_global_load_lds(
      (__attribute__((address_space(1))) void*)(uintptr_t)g,
      (__attribute__((address_space(3))) void*)(uintptr_t)l,
      16, 0, 0);
}

// tanh-approx GELU (max |err| vs exact ~3e-3); tanh via v_exp_f32
__device__ __forceinline__ float gelu_f(float x) {
  float u = x * (0.7978845608f + 0.0356774081f * x * x);
  float t = 1.0f - 2.0f / (__expf(2.0f * u) + 1.0f);
  return 0.5f * x * (1.0f + t);
}

// ------- weight -> MFMA-fragment layout (B-operand order), all 4 weights -----
__global__ __launch_bounds__(256) void make_frags_kernel(
    const float* __restrict__ w_qkv, const float* __restrict__ w_o,
    const float* __restrict__ w1, const float* __restrict__ w2,
    bf16* __restrict__ fqkv, bf16* __restrict__ fwo, bf16* __restrict__ fw1,
    bf16* __restrict__ fw2) {
  int chunk = blockIdx.x * 4 + (threadIdx.x >> 6);
  int lane = threadIdx.x & 63;
  const float* src;
  bf16* dst;
  int K, N, base;
  if (chunk < 3456) {
    src = w_qkv; dst = fqkv; K = 768; N = 2304; base = 0;
  } else if (chunk < 4608) {
    src = w_o; dst = fwo; K = 768; N = 768; base = 3456;
  } else if (chunk < 9216) {
    src = w1; dst = fw1; K = 768; N = 3072; base = 4608;
  } else {
    src = w2; dst = fw2; K = 3072; N = 768; base = 9216;
  }
  int lid = chunk - base;
  int kc = K / 32;
  int n16 = lid / kc, c = lid - n16 * kc;
  int lr = lane & 15, qd = lane >> 4;
  int n = n16 * 16 + lr;
  int k0 = c * 32 + qd * 8;
  bf16x8 v;
#pragma unroll
  for (int e = 0; e < 8; e++) v[e] = (bf16)src[(size_t)(k0 + e) * N + n];
  *(bf16x8*)&dst[(size_t)lid * 512 + lane * 8] = v;
}

// ---------------- layernorm (f32 in -> bf16 out), one wave per row ------------
__global__ __launch_bounds__(256) void ln_kernel(
    const float* __restrict__ x, const float* __restrict__ g,
    const float* __restrict__ b, bf16* __restrict__ ob) {
  int w = threadIdx.x >> 6, lane = threadIdx.x & 63;
  size_t row = (size_t)blockIdx.x * 4 + w;
  const float* xr = x + row * 768;
  float4 v[3];
  float s = 0.f, sq = 0.f;
#pragma unroll
  for (int k = 0; k < 3; k++) {
    v[k] = *(const float4*)(xr + (k * 64 + lane) * 4);
    s += v[k].x + v[k].y + v[k].z + v[k].w;
    sq += v[k].x * v[k].x + v[k].y * v[k].y + v[k].z * v[k].z + v[k].w * v[k].w;
  }
#pragma unroll
  for (int off = 32; off >= 1; off >>= 1) {
    s += __shfl_xor(s, off);
    sq += __shfl_xor(sq, off);
  }
  float mean = s * (1.f / 768.f);
  float rstd = rsqrtf(sq * (1.f / 768.f) - mean * mean + 1e-5f);
#pragma unroll
  for (int k = 0; k < 3; k++) {
    int c = (k * 64 + lane) * 4;
    float4 gg = *(const float4*)(g + c);
    float4 bb = *(const float4*)(b + c);
    bf16x4 pk = {(bf16)((v[k].x - mean) * rstd * gg.x + bb.x),
                 (bf16)((v[k].y - mean) * rstd * gg.y + bb.y),
                 (bf16)((v[k].z - mean) * rstd * gg.z + bb.z),
                 (bf16)((v[k].w - mean) * rstd * gg.w + bb.w)};
    *(bf16x4*)(ob + row * 768 + c) = pk;
  }
}

// ------- ln2_reduce: t = p0+p1+b_o+x(resid f32); x2=t (bf16); h2 = LN(t) bf16 -
__global__ __launch_bounds__(256) void ln2_reduce_kernel(
    const bf16* __restrict__ p, const float* __restrict__ bo,
    const float* __restrict__ xres, const float* __restrict__ g,
    const float* __restrict__ b, bf16* __restrict__ x2,
    bf16* __restrict__ h2) {
  int w = threadIdx.x >> 6, lane = threadIdx.x & 63;
  size_t row = (size_t)blockIdx.x * 4 + w;
  const bf16* p0 = p + row * 768;
  const bf16* p1 = p0 + (size_t)M_TOK * 768;
  const float* xr = xres + row * 768;
  float4 v[3];
  float s = 0.f, sq = 0.f;
#pragma unroll
  for (int k = 0; k < 3; k++) {
    int c = (k * 64 + lane) * 4;
    bf16x4 a0 = *(const bf16x4*)(p0 + c);
    bf16x4 a1 = *(const bf16x4*)(p1 + c);
    float4 bb = *(const float4*)(bo + c);
    float4 rr = *(const float4*)(xr + c);
    v[k].x = (float)a0[0] + (float)a1[0] + bb.x + rr.x;
    v[k].y = (float)a0[1] + (float)a1[1] + bb.y + rr.y;
    v[k].z = (float)a0[2] + (float)a1[2] + bb.z + rr.z;
    v[k].w = (float)a0[3] + (float)a1[3] + bb.w + rr.w;
    bf16x4 xo = {(bf16)v[k].x, (bf16)v[k].y, (bf16)v[k].z, (bf16)v[k].w};
    *(bf16x4*)(x2 + row * 768 + c) = xo;
    s += v[k].x + v[k].y + v[k].z + v[k].w;
    sq += v[k].x * v[k].x + v[k].y * v[k].y + v[k].z * v[k].z + v[k].w * v[k].w;
  }
#pragma unroll
  for (int off = 32; off >= 1; off >>= 1) {
    s += __shfl_xor(s, off);
    sq += __shfl_xor(sq, off);
  }
  float mean = s * (1.f / 768.f);
  float rstd = rsqrtf(sq * (1.f / 768.f) - mean * mean + 1e-5f);
#pragma unroll
  for (int k = 0; k < 3; k++) {
    int c = (k * 64 + lane) * 4;
    float4 gg = *(const float4*)(g + c);
    float4 bb = *(const float4*)(b + c);
    bf16x4 pk = {(bf16)((v[k].x - mean) * rstd * gg.x + bb.x),
                 (bf16)((v[k].y - mean) * rstd * gg.y + bb.y),
                 (bf16)((v[k].z - mean) * rstd * gg.z + bb.z),
                 (bf16)((v[k].w - mean) * rstd * gg.w + bb.w)};
    *(bf16x4*)(h2 + row * 768 + c) = pk;
  }
}

// ------- ln3_reduce: t = gelu(p0+p1+b2)+x2(bf16); out = LN(t) f32 -------------
__global__ __launch_bounds__(256) void ln3_reduce_kernel(
    const bf16* __restrict__ p, const float* __restrict__ b2,
    const bf16* __restrict__ x2, const float* __restrict__ g,
    const float* __restrict__ b, float* __restrict__ out) {
  int w = threadIdx.x >> 6, lane = threadIdx.x & 63;
  size_t row = (size_t)blockIdx.x * 4 + w;
  const bf16* p0 = p + row * 768;
  const bf16* p1 = p0 + (size_t)M_TOK * 768;
  const bf16* xr = x2 + row * 768;
  float4 v[3];
  float s = 0.f, sq = 0.f;
#pragma unroll
  for (int k = 0; k < 3; k++) {
    int c = (k * 64 + lane) * 4;
    bf16x4 a0 = *(const bf16x4*)(p0 + c);
    bf16x4 a1 = *(const bf16x4*)(p1 + c);
    float4 bb = *(const float4*)(b2 + c);
    bf16x4 rr = *(const bf16x4*)(xr + c);
    v[k].x = gelu_f((float)a0[0] + (float)a1[0] + bb.x) + (float)rr[0];
    v[k].y = gelu_f((float)a0[1] + (float)a1[1] + bb.y) + (float)rr[1];
    v[k].z = gelu_f((float)a0[2] + (float)a1[2] + bb.z) + (float)rr[2];
    v[k].w = gelu_f((float)a0[3] + (float)a1[3] + bb.w) + (float)rr[3];
    s += v[k].x + v[k].y + v[k].z + v[k].w;
    sq += v[k].x * v[k].x + v[k].y * v[k].y + v[k].z * v[k].z + v[k].w * v[k].w;
  }
#pragma unroll
  for (int off = 32; off >= 1; off >>= 1) {
    s += __shfl_xor(s, off);
    sq += __shfl_xor(sq, off);
  }
  float mean = s * (1.f / 768.f);
  float rstd = rsqrtf(sq * (1.f / 768.f) - mean * mean + 1e-5f);
#pragma unroll
  for (int k = 0; k < 3; k++) {
    int c = (k * 64 + lane) * 4;
    float4 gg = *(const float4*)(g + c);
    float4 bb = *(const float4*)(b + c);
    float4 ov = {(v[k].x - mean) * rstd * gg.x + bb.x,
                 (v[k].y - mean) * rstd * gg.y + bb.y,
                 (v[k].z - mean) * rstd * gg.z + bb.z,
                 (v[k].w - mean) * rstd * gg.w + bb.w};
    *(float4*)(out + row * 768 + c) = ov;
  }
}

// ---------------- GEMM: C = A @ B^T, 256x256 8-phase (m201 geometry) ----------
// ROUND-4: R1-R3 tuned the schedule of a geometry that is LDS-BW-bound:
// 64x64/wave (4x4 frags) needs 128KB ds_read per K-tile vs 1242 cyc of MFMA
// -> ~50% ceiling, 26% observed. New geometry: BM=BN=256, BK=64, 8 waves
// (2Mx4N), per-wave 128x64 (8x4 frags) -> 192KB reads vs 2483 cyc MFMA
// (ratio 1.6 -> 0.92). 2 LDS buffers x 64KB (A: 2 halves x 128rows x 64k
// chunk-swizzled; B: 2 halves x 8 n16-chunks x 2 c x 512, fragment-linear).
// 8 phases per 2 K-tiles; phase = {4-8 ds_reads || stage 1 half-tile (2 gld)
// -> barrier -> lgkm(0) -> setprio(1) 16 MFMA} ; counted vmcnt(2) at phases
// 4/8 only (never 0 mid-loop). Stage stream per iter (tiles T,T+1):
//   ph1:A0(T+1) ph2:A1(T+1) ph3:B1(T+1) | ph4:B0(T+2) ph5:A0(T+2)
//   ph6:A1(T+2) ph7:B1(T+2) | ph8:B0(T+3)
// Every slot is re-staged exactly one phase after its end-barrier free point
// (B frees after its k2=1 phase, A after its Mh1/k2=1 phase); vmcnt(2)@ph4
// gates T+1 complete before ph5, vmcnt(2)@ph8 gates T+2 before next ph1.
// K-accumulation order per output element is unchanged vs R3.
template <int EPI, int LDA, int KTOT, int KSL, int NN>
__global__ __launch_bounds__(512, 2) void gemm256_kernel(
    const bf16* __restrict__ A, const bf16* __restrict__ Bf,
    const float* __restrict__ bias, bf16* __restrict__ outb,
    bf16* __restrict__ qo, bf16* __restrict__ ko, bf16* __restrict__ vto) {
  constexpr int KCg = KTOT / 32;   // B frag chunks per n16 row
  constexpr int NT = KSL / 64;     // K-tiles: 12 / 6 / 24 (all even)
  constexpr int NI = NT / 2;
  __shared__ __align__(16) bf16 smem[2][32768];  // 2 x 64KB
  int tid = threadIdx.x;
  int w = tid >> 6, l = tid & 63;
  int qd = l >> 4, lr = l & 15;
  int bm0 = blockIdx.x * 256, bn0 = blockIdx.y * 256;
  int kbase = blockIdx.z * KSL;
  int wm = (w >> 2) * 128;   // wave M offset (2 groups)
  int wnl = (w & 3) * 4;     // wave N offset in 16-col frags (4 groups)
  int ah = wm >> 7;          // which A-half this wave reads

  // staging sources (per-lane; LDS dest wave-uniform, lane*16B linear)
  const bf16* pA = A + (size_t)(bm0 + w * 8 + (l >> 3)) * LDA + kbase +
                   ((l & 7) ^ (l >> 3)) * 8;   // pre-swizzled source chunk
  const bf16* pB =
      Bf + ((size_t)((bn0 >> 4) + w) * KCg + (kbase >> 5)) * 512 + l * 8;

  auto STG_A = [&](int t, int h, bf16* buf) {   // one A half-tile: 2 glds
    const bf16* s = pA + (size_t)(h * 128) * LDA + t * 64;
    bf16* d = buf + h * 8192 + w * 512;
    gld_lds16(s, d);
    gld_lds16(s + (size_t)64 * LDA, d + 4096);
  };
  auto STG_B = [&](int t, int h, bf16* buf) {   // one B half-tile: 2 glds
    const bf16* s = pB + ((size_t)h * 8 * KCg + t * 2) * 512;
    bf16* d = buf + 16384 + h * 8192 + w * 1024;
    gld_lds16(s, d);
    gld_lds16(s + 512, d + 512);
  };
  auto LD_A4 = [&](const bf16* buf, int i0, int k2, bf16x8* af) {
#pragma unroll
    for (int i = 0; i < 4; ++i) {
      int r = (i0 + i) * 16 + lr;
      af[i] = *(const bf16x8*)(buf + ah * 8192 + r * 64 +
                               ((k2 * 4 + qd) ^ (r & 7)) * 8);
    }
  };
  auto LD_B4 = [&](const bf16* buf, int k2, bf16x8* bv) {
#pragma unroll
    for (int j = 0; j < 4; ++j) {
      int n16 = wnl + j;
      bv[j] = *(const bf16x8*)(buf + 16384 + (n16 >> 3) * 8192 +
                               ((n16 & 7) * 2 + k2) * 512 + l * 8);
    }
  };

  f32x4 acc[8][4] = {};
  auto MM = [&](bf16x8* af, bf16x8* bv, int i0) {
#pragma unroll
    for (int i = 0; i < 4; ++i)
#pragma unroll
      for (int j = 0; j < 4; ++j)
        acc[i0 + i][j] = __builtin_amdgcn_mfma_f32_16x16x32_bf16(
            af[i], bv[j], acc[i0 + i][j], 0, 0, 0);
  };

  // ---- prologue: tile0 complete + B0(1); leave B0(1) in flight ----
  STG_A(0, 0, smem[0]); STG_A(0, 1, smem[0]);
  STG_B(0, 0, smem[0]); STG_B(0, 1, smem[0]);
  STG_B(1, 0, smem[1]);
  asm volatile("s_waitcnt vmcnt(2)" ::: "memory");
  __builtin_amdgcn_sched_barrier(0);
  __builtin_amdgcn_s_barrier();
  __builtin_amdgcn_sched_barrier(0);

  bf16x8 af[4], bv[4];

#pragma unroll 1
  for (int it = 0; it < NI; ++it) {
    const int T = 2 * it;
    bf16* b0 = smem[0];
    bf16* b1 = smem[1];
    const bool s2 = (it + 1 < NI);

    // ============ tile T (buf0), phases 1-4 ============
    // ph1: k2=0, Mh0
    __builtin_amdgcn_sched_barrier(0);
    LD_B4(b0, 0, bv);
    LD_A4(b0, 0, 0, af);
    __builtin_amdgcn_sched_barrier(0);
    STG_A(T + 1, 0, b1);
    __builtin_amdgcn_sched_barrier(0);
    __builtin_amdgcn_s_barrier();
    asm volatile("s_waitcnt lgkmcnt(0)" ::: "memory");
    __builtin_amdgcn_sched_barrier(0);
    __builtin_amdgcn_s_setprio(1);
    MM(af, bv, 0);
    __builtin_amdgcn_s_setprio(0);
    __builtin_amdgcn_sched_barrier(0);
    __builtin_amdgcn_s_barrier();

    // ph2: k2=0, Mh1
    __builtin_amdgcn_sched_barrier(0);
    LD_A4(b0, 4, 0, af);
    __builtin_amdgcn_sched_barrier(0);
    STG_A(T + 1, 1, b1);
    __builtin_amdgcn_sched_barrier(0);
    __builtin_amdgcn_s_barrier();
    asm volatile("s_waitcnt lgkmcnt(0)" ::: "memory");
    __builtin_amdgcn_sched_barrier(0);
    __builtin_amdgcn_s_setprio(1);
    MM(af, bv, 4);
    __builtin_amdgcn_s_setprio(0);
    __builtin_amdgcn_sched_barrier(0);
    __builtin_amdgcn_s_barrier();

    // ph3: k2=1, Mh0
    __builtin_amdgcn_sched_barrier(0);
    LD_B4(b0, 1, bv);
    LD_A4(b0, 0, 1, af);
    __builtin_amdgcn_sched_barrier(0);
    STG_B(T + 1, 1, b1);
    __builtin_amdgcn_sched_barrier(0);
    __builtin_amdgcn_s_barrier();
    asm volatile("s_waitcnt lgkmcnt(0)" ::: "memory");
    __builtin_amdgcn_sched_barrier(0);
    __builtin_amdgcn_s_setprio(1);
    MM(af, bv, 0);
    __builtin_amdgcn_s_setprio(0);
    __builtin_amdgcn_sched_barrier(0);
    __builtin_amdgcn_s_barrier();

    // ph4: k2=1, Mh1  [vmcnt gate: T+1 complete before ph5]
    __builtin_amdgcn_sched_barrier(0);
    LD_A4(b0, 4, 1, af);
    __builtin_amdgcn_sched_barrier(0);
    if (s2) STG_B(T + 2, 0, b0);
    __builtin_amdgcn_sched_barrier(0);
    __builtin_amdgcn_s_barrier();
    asm volatile("s_waitcnt lgkmcnt(0)" ::: "memory");
    __builtin_amdgcn_sched_barrier(0);
    __builtin_amdgcn_s_setprio(1);
    MM(af, bv, 4);
    __builtin_amdgcn_s_setprio(0);
    __builtin_amdgcn_sched_barrier(0);
    if (s2) asm volatile("s_waitcnt vmcnt(2)" ::: "memory");
    else    asm volatile("s_waitcnt vmcnt(0)" ::: "memory");
    __builtin_amdgcn_sched_barrier(0);
    __builtin_amdgcn_s_barrier();

    // ============ tile T+1 (buf1), phases 5-8 ============
    // ph5: k2=0, Mh0
    __builtin_amdgcn_sched_barrier(0);
    LD_B4(b1, 0, bv);
    LD_A4(b1, 0, 0, af);
    __builtin_amdgcn_sched_barrier(0);
    if (s2) STG_A(T + 2, 0, b0);
    __builtin_amdgcn_sched_barrier(0);
    __builtin_amdgcn_s_barrier();
    asm volatile("s_waitcnt lgkmcnt(0)" ::: "memory");
    __builtin_amdgcn_sched_barrier(0);
    __builtin_amdgcn_s_setprio(1);
    MM(af, bv, 0);
    __builtin_amdgcn_s_setprio(0);
    __builtin_amdgcn_sched_barrier(0);
    __builtin_amdgcn_s_barrier();

    // ph6: k2=0, Mh1
    __builtin_amdgcn_sched_barrier(0);
    LD_A4(b1, 4, 0, af);
    __builtin_amdgcn_sched_barrier(0);
    if (s2) STG_A(T + 2, 1, b0);
    __builtin_amdgcn_sched_barrier(0);
    __builtin_amdgcn_s_barrier();
    asm volatile("s_waitcnt lgkmcnt(0)" ::: "memory");
    __builtin_amdgcn_sched_barrier(0);
    __builtin_amdgcn_s_setprio(1);
    MM(af, bv, 4);
    __builtin_amdgcn_s_setprio(0);
    __builtin_amdgcn_sched_barrier(0);
    __builtin_amdgcn_s_barrier();

    // ph7: k2=1, Mh0
    __builtin_amdgcn_sched_barrier(0);
    LD_B4(b1, 1, bv);
    LD_A4(b1, 0, 1, af);
    __builtin_amdgcn_sched_barrier(0);
    if (s2) STG_B(T + 2, 1, b0);
    __builtin_amdgcn_sched_barrier(0);
    __builtin_amdgcn_s_barrier();
    asm volatile("s_waitcnt lgkmcnt(0)" ::: "memory");
    __builtin_amdgcn_sched_barrier(0);
    __builtin_amdgcn_s_setprio(1);
    MM(af, bv, 0);
    __builtin_amdgcn_s_setprio(0);
    __builtin_amdgcn_sched_barrier(0);
    __builtin_amdgcn_s_barrier();

    // ph8: k2=1, Mh1  [vmcnt gate: T+2 complete before next ph1]
    __builtin_amdgcn_sched_barrier(0);
    LD_A4(b1, 4, 1, af);
    __builtin_amdgcn_sched_barrier(0);
    if (s2) STG_B(T + 3, 0, b1);
    __builtin_amdgcn_sched_barrier(0);
    __builtin_amdgcn_s_barrier();
    asm volatile("s_waitcnt lgkmcnt(0)" ::: "memory");
    __builtin_amdgcn_sched_barrier(0);
    __builtin_amdgcn_s_setprio(1);
    MM(af, bv, 4);
    __builtin_amdgcn_s_setprio(0);
    __builtin_amdgcn_sched_barrier(0);
    if (s2) asm volatile("s_waitcnt vmcnt(2)" ::: "memory");
    else    asm volatile("s_waitcnt vmcnt(0)" ::: "memory");
    __builtin_amdgcn_sched_barrier(0);
    __builtin_amdgcn_s_barrier();
  }

  // ---- epilogue ----
  bf16* outbs = (EPI == 5) ? outb + (size_t)blockIdx.z * M_TOK * NN : outb;

#pragma unroll
  for (int i = 0; i < 8; i++) {
#pragma unroll
    for (int j = 0; j < 4; j++) {
      if (EPI == 4) {
        // fused qkv split (NN==2304). 16-col tiles never straddle head bounds.
        int colt = bn0 + (wnl + j) * 16;
        int which = colt / 768;
        int rem = colt - which * 768;
        int h = rem / 96;
        int dhb = rem - h * 96;
        int row0 = bm0 + wm + i * 16 + qd * 4;
        int b = row0 >> 10, n0 = row0 & 1023;
        int bh = b * 8 + h;
        if (which == 2) {
          bf16x4 pk = {(bf16)acc[i][j][0], (bf16)acc[i][j][1],
                       (bf16)acc[i][j][2], (bf16)acc[i][j][3]};
          *(bf16x4*)(vto + ((size_t)(bh * 96 + dhb + lr)) * 1024 + n0) = pk;
        } else if (which == 0) {
          // q pre-scaled by 1/sqrt(dh) so attention skips the S-scale
#pragma unroll
          for (int r = 0; r < 4; r++)
            qo[((size_t)bh * 1024 + n0 + r) * 96 + dhb + lr] =
                (bf16)(acc[i][j][r] * SCALE_);
        } else {
#pragma unroll
          for (int r = 0; r < 4; r++)
            ko[((size_t)bh * 1024 + n0 + r) * 96 + dhb + lr] =
                (bf16)acc[i][j][r];
        }
      } else {
#pragma unroll
        for (int r = 0; r < 4; r++) {
          int row = bm0 + wm + i * 16 + qd * 4 + r;
          int col = bn0 + (wnl + j) * 16 + lr;
          size_t o = (size_t)row * NN + col;
          float v = acc[i][j][r];
          if (EPI == 2) {
            outbs[o] = (bf16)gelu_f(v + bias[col]);
          } else {  // EPI == 5
            outbs[o] = (bf16)v;
          }
        }
      }
    }
  }
}

// ---------------- fused attention, 128 q-rows/block, 64-key tiles -------------
__global__ __launch_bounds__(256) void attn_kernel(
    const bf16* __restrict__ qb, const bf16* __restrict__ kb,
    const bf16* __restrict__ vtb, bf16* __restrict__ operm) {
  __shared__ __align__(16) bf16 Ks[2][64 * 104];   // [key][dh], pad 104
  __shared__ __align__(16) bf16 Vs[2][96 * 72];    // [dh][key], pad 72
  __shared__ __align__(16) bf16 Ps[128 * 72];      // [qrow][key], pad 72
  int t = threadIdx.x;
  int w = t >> 6, lane = t & 63;
  int qd = lane >> 4, lr = lane & 15;
  int bh = blockIdx.x, nt0 = blockIdx.y * 128;
  int bq = bh >> 3, hh = bh & 7;

  const bf16* kgb = kb + (size_t)bh * 1024 * 96;
  const bf16* vgb = vtb + (size_t)bh * 96 * 1024;

  bf16x8 kreg[3], vreg[3];
#pragma unroll
  for (int it = 0; it < 3; it++) {
    int idx = it * 256 + t;
    kreg[it] = *(const bf16x8*)(kgb + (idx / 12) * 96 + (idx % 12) * 8);
    vreg[it] = *(const bf16x8*)(vgb + (size_t)(idx >> 3) * 1024 + (idx & 7) * 8);
  }

  const bf16* qg = qb + ((size_t)bh * 1024 + nt0 + w * 32) * 96;
  bf16x8 afq[2][3];
#pragma unroll
  for (int i = 0; i < 2; i++)
#pragma unroll
    for (int ks = 0; ks < 3; ks++)
      afq[i][ks] = *(const bf16x8*)(qg + (i * 16 + lr) * 96 + ks * 32 + qd * 8);

  f32x4 oacc[2][6] = {};
  float lst[2][4] = {};

  int cur = 0;
  for (int kt = 0; kt < 16; kt++) {
#pragma unroll
    for (int it = 0; it < 3; it++) {
      int idx = it * 256 + t;
      *(bf16x8*)&Ks[cur][(idx / 12) * 104 + (idx % 12) * 8] = kreg[it];
      *(bf16x8*)&Vs[cur][(idx >> 3) * 72 + (idx & 7) * 8] = vreg[it];
    }
    if (kt < 15) {
      const bf16* kg = kgb + (size_t)(kt + 1) * 64 * 96;
      const bf16* vg = vgb + (kt + 1) * 64;
#pragma unroll
      for (int it = 0; it < 3; it++) {
        int idx = it * 256 + t;
        kreg[it] = *(const bf16x8*)(kg + (idx / 12) * 96 + (idx % 12) * 8);
        vreg[it] =
            *(const bf16x8*)(vg + (size_t)(idx >> 3) * 1024 + (idx & 7) * 8);
      }
    }
    __syncthreads();

    f32x4 sacc[2][4] = {};
#pragma unroll
    for (int ks = 0; ks < 3; ks++) {
      bf16x8 bk[4];
#pragma unroll
      for (int jn = 0; jn < 4; jn++)
        bk[jn] =
            *(const bf16x8*)&Ks[cur][(jn * 16 + lr) * 104 + ks * 32 + qd * 8];
#pragma unroll
      for (int i = 0; i < 2; i++)
#pragma unroll
        for (int jn = 0; jn < 4; jn++)
          sacc[i][jn] = __builtin_amdgcn_mfma_f32_16x16x32_bf16(
              afq[i][ks], bk[jn], sacc[i][jn], 0, 0, 0);
    }

#pragma unroll
    for (int i = 0; i < 2; i++)
#pragma unroll
      for (int jn = 0; jn < 4; jn++)
#pragma unroll
        for (int r = 0; r < 4; r++) {
          float p = __expf(sacc[i][jn][r]);
          lst[i][r] += p;
          Ps[(w * 32 + i * 16 + qd * 4 + r) * 72 + jn * 16 + lr] = (bf16)p;
        }

#pragma unroll
    for (int ks = 0; ks < 2; ks++) {
      bf16x8 ap[2];
#pragma unroll
      for (int i = 0; i < 2; i++)
        ap[i] =
            *(const bf16x8*)&Ps[(w * 32 + i * 16 + lr) * 72 + ks * 32 + qd * 8];
#pragma unroll
      for (int jn = 0; jn < 6; jn++) {
        bf16x8 bv =
            *(const bf16x8*)&Vs[cur][(jn * 16 + lr) * 72 + ks * 32 + qd * 8];
#pragma unroll
        for (int i = 0; i < 2; i++)
          oacc[i][jn] = __builtin_amdgcn_mfma_f32_16x16x32_bf16(
              ap[i], bv, oacc[i][jn], 0, 0, 0);
      }
    }
    cur ^= 1;
  }

#pragma unroll
  for (int i = 0; i < 2; i++)
#pragma unroll
    for (int r = 0; r < 4; r++) {
#pragma unroll
      for (int off = 1; off < 16; off <<= 1)
        lst[i][r] += __shfl_xor(lst[i][r], off);
    }

#pragma unroll
  for (int i = 0; i < 2; i++) {
#pragma unroll
    for (int r = 0; r < 4; r++) {
      float inv = 1.0f / lst[i][r];
      int n = nt0 + w * 32 + i * 16 + qd * 4 + r;
      size_t rowo = (size_t)bq * 1024 + hh * 128 + (n >> 3);
      int colb = 96 * (n & 7);
#pragma unroll
      for (int jn = 0; jn < 6; jn++)
        operm[rowo * 768 + colb + jn * 16 + lr] =
            (bf16)(oacc[i][jn][r] * inv);
    }
  }
}

// ------------------------------------------------------------------------------
extern "C" void kernel_launch(void* const* d_in, const int* in_sizes, int n_in,
                              void* d_out, int out_size, void* d_ws,
                              size_t ws_size, hipStream_t stream) {
  const float* x = (const float*)d_in[0];
  const float* w_qkv = (const float*)d_in[1];
  const float* w_o = (const float*)d_in[2];
  const float* b_o = (const float*)d_in[3];
  const float* w1 = (const float*)d_in[4];
  const float* b1 = (const float*)d_in[5];
  const float* w2 = (const float*)d_in[6];
  const float* b2 = (const float*)d_in[7];
  const float* g1 = (const float*)d_in[8];
  const float* be1 = (const float*)d_in[9];
  const float* gm = (const float*)d_in[10];
  const float* bm = (const float*)d_in[11];
  const float* g3 = (const float*)d_in[12];
  const float* be3 = (const float*)d_in[13];

  char* ws = (char*)d_ws;
  size_t off = 0;
  auto alloc = [&](size_t bytes) {
    char* p = ws + off;
    off += (bytes + 255) & ~(size_t)255;
    return p;
  };
  const size_t SZ_TOK_BF = (size_t)M_TOK * 768 * 2;   // 12.58 MB
  bf16* fqkv = (bf16*)alloc((size_t)2304 * 768 * 2);
  bf16* fwo = (bf16*)alloc((size_t)768 * 768 * 2);
  bf16* fw1 = (bf16*)alloc((size_t)3072 * 768 * 2);
  bf16* fw2 = (bf16*)alloc((size_t)768 * 3072 * 2);
  bf16* hA = (bf16*)alloc(SZ_TOK_BF);   // LN1 out; then operm; then h2
  bf16* qb = (bf16*)alloc(SZ_TOK_BF);
  bf16* kbuf = (bf16*)alloc(SZ_TOK_BF);
  bf16* vtb = (bf16*)alloc(SZ_TOK_BF);
  bf16* x2 = (bf16*)alloc(SZ_TOK_BF);
  char* G = alloc((size_t)M_TOK * 3072 * 2);
  bf16* operm = hA;
  bf16* h2 = hA;
  bf16* pWo = (bf16*)G;
  bf16* a1 = (bf16*)G;
  bf16* pW2 = hA;  // spans hA+qb (2 x 12.58 MB), live after a1's last read

  make_frags_kernel<<<3456, 256, 0, stream>>>(w_qkv, w_o, w1, w2, fqkv, fwo,
                                              fw1, fw2);

  ln_kernel<<<M_TOK / 4, 256, 0, stream>>>(x, g1, be1, hA);

  // QKV GEMM with fused head-split epilogue (q pre-scaled by 1/sqrt(dh))
  gemm256_kernel<4, 768, 768, 768, 2304><<<dim3(32, 9), 512, 0, stream>>>(
      hA, fqkv, nullptr, nullptr, qb, kbuf, vtb);

  attn_kernel<<<dim3(64, 8), 256, 0, stream>>>(qb, kbuf, vtb, operm);

  // Wo GEMM, split-K=2 (slices of 384) -> bf16 partials in G
  gemm256_kernel<5, 768, 768, 384, 768><<<dim3(32, 3, 2), 512, 0, stream>>>(
      operm, fwo, nullptr, pWo, nullptr, nullptr, nullptr);

  ln2_reduce_kernel<<<M_TOK / 4, 256, 0, stream>>>(pWo, b_o, x, gm, bm, x2, h2);

  // W1 GEMM: bias + GELU -> bf16 a1
  gemm256_kernel<2, 768, 768, 768, 3072><<<dim3(32, 12), 512, 0, stream>>>(
      h2, fw1, b1, a1, nullptr, nullptr, nullptr);

  // W2 GEMM, split-K=2 (slices of 1536) -> bf16 partials spanning hA+qb
  gemm256_kernel<5, 3072, 3072, 1536, 768><<<dim3(32, 3, 2), 512, 0, stream>>>(
      a1, fw2, nullptr, pW2, nullptr, nullptr, nullptr);

  ln3_reduce_kernel<<<M_TOK / 4, 256, 0, stream>>>(pW2, b2, x2, g3, be3,
                                                   (float*)d_out);
}

// Round 5
// 323.913 us; speedup vs baseline: 1.1053x; 1.1053x over previous
//
#include <hip/hip_runtime.h>
#include <cmath>
#include <cstdint>

typedef __bf16 bf16;
typedef __bf16 bf16x8 __attribute__((ext_vector_type(8)));
typedef __bf16 bf16x4 __attribute__((ext_vector_type(4)));
typedef float  f32x4  __attribute__((ext_vector_type(4)));

#define M_TOK 8192
#define SCALE_ 0.10206207261596575f   // 96^-0.5

__device__ __forceinline__ void gld_lds16(const void* g, void* l) {
  __builtin_amdgcn_global_load_lds(
      (__attribute__((address_space(1))) void*)(uintptr_t)g,
      (__attribute__((address_space(3))) void*)(uintptr_t)l,
      16, 0, 0);
}

// tanh-approx GELU (max |err| vs exact ~3e-3); tanh via v_exp_f32
__device__ __forceinline__ float gelu_f(float x) {
  float u = x * (0.7978845608f + 0.0356774081f * x * x);
  float t = 1.0f - 2.0f / (__expf(2.0f * u) + 1.0f);
  return 0.5f * x * (1.0f + t);
}

// ------- weight -> MFMA-fragment layout (B-operand order), all 4 weights -----
__global__ __launch_bounds__(256) void make_frags_kernel(
    const float* __restrict__ w_qkv, const float* __restrict__ w_o,
    const float* __restrict__ w1, const float* __restrict__ w2,
    bf16* __restrict__ fqkv, bf16* __restrict__ fwo, bf16* __restrict__ fw1,
    bf16* __restrict__ fw2) {
  int chunk = blockIdx.x * 4 + (threadIdx.x >> 6);
  int lane = threadIdx.x & 63;
  const float* src;
  bf16* dst;
  int K, N, base;
  if (chunk < 3456) {
    src = w_qkv; dst = fqkv; K = 768; N = 2304; base = 0;
  } else if (chunk < 4608) {
    src = w_o; dst = fwo; K = 768; N = 768; base = 3456;
  } else if (chunk < 9216) {
    src = w1; dst = fw1; K = 768; N = 3072; base = 4608;
  } else {
    src = w2; dst = fw2; K = 3072; N = 768; base = 9216;
  }
  int lid = chunk - base;
  int kc = K / 32;
  int n16 = lid / kc, c = lid - n16 * kc;
  int lr = lane & 15, qd = lane >> 4;
  int n = n16 * 16 + lr;
  int k0 = c * 32 + qd * 8;
  bf16x8 v;
#pragma unroll
  for (int e = 0; e < 8; e++) v[e] = (bf16)src[(size_t)(k0 + e) * N + n];
  *(bf16x8*)&dst[(size_t)lid * 512 + lane * 8] = v;
}

// ---------------- layernorm (f32 in -> bf16 out), one wave per row ------------
__global__ __launch_bounds__(256) void ln_kernel(
    const float* __restrict__ x, const float* __restrict__ g,
    const float* __restrict__ b, bf16* __restrict__ ob) {
  int w = threadIdx.x >> 6, lane = threadIdx.x & 63;
  size_t row = (size_t)blockIdx.x * 4 + w;
  const float* xr = x + row * 768;
  float4 v[3];
  float s = 0.f, sq = 0.f;
#pragma unroll
  for (int k = 0; k < 3; k++) {
    v[k] = *(const float4*)(xr + (k * 64 + lane) * 4);
    s += v[k].x + v[k].y + v[k].z + v[k].w;
    sq += v[k].x * v[k].x + v[k].y * v[k].y + v[k].z * v[k].z + v[k].w * v[k].w;
  }
#pragma unroll
  for (int off = 32; off >= 1; off >>= 1) {
    s += __shfl_xor(s, off);
    sq += __shfl_xor(sq, off);
  }
  float mean = s * (1.f / 768.f);
  float rstd = rsqrtf(sq * (1.f / 768.f) - mean * mean + 1e-5f);
#pragma unroll
  for (int k = 0; k < 3; k++) {
    int c = (k * 64 + lane) * 4;
    float4 gg = *(const float4*)(g + c);
    float4 bb = *(const float4*)(b + c);
    bf16x4 pk = {(bf16)((v[k].x - mean) * rstd * gg.x + bb.x),
                 (bf16)((v[k].y - mean) * rstd * gg.y + bb.y),
                 (bf16)((v[k].z - mean) * rstd * gg.z + bb.z),
                 (bf16)((v[k].w - mean) * rstd * gg.w + bb.w)};
    *(bf16x4*)(ob + row * 768 + c) = pk;
  }
}

// ------- ln2_reduce: t = p0+p1+b_o+x(resid f32); x2=t (bf16); h2 = LN(t) bf16 -
__global__ __launch_bounds__(256) void ln2_reduce_kernel(
    const bf16* __restrict__ p, const float* __restrict__ bo,
    const float* __restrict__ xres, const float* __restrict__ g,
    const float* __restrict__ b, bf16* __restrict__ x2,
    bf16* __restrict__ h2) {
  int w = threadIdx.x >> 6, lane = threadIdx.x & 63;
  size_t row = (size_t)blockIdx.x * 4 + w;
  const bf16* p0 = p + row * 768;
  const bf16* p1 = p0 + (size_t)M_TOK * 768;
  const float* xr = xres + row * 768;
  float4 v[3];
  float s = 0.f, sq = 0.f;
#pragma unroll
  for (int k = 0; k < 3; k++) {
    int c = (k * 64 + lane) * 4;
    bf16x4 a0 = *(const bf16x4*)(p0 + c);
    bf16x4 a1 = *(const bf16x4*)(p1 + c);
    float4 bb = *(const float4*)(bo + c);
    float4 rr = *(const float4*)(xr + c);
    v[k].x = (float)a0[0] + (float)a1[0] + bb.x + rr.x;
    v[k].y = (float)a0[1] + (float)a1[1] + bb.y + rr.y;
    v[k].z = (float)a0[2] + (float)a1[2] + bb.z + rr.z;
    v[k].w = (float)a0[3] + (float)a1[3] + bb.w + rr.w;
    bf16x4 xo = {(bf16)v[k].x, (bf16)v[k].y, (bf16)v[k].z, (bf16)v[k].w};
    *(bf16x4*)(x2 + row * 768 + c) = xo;
    s += v[k].x + v[k].y + v[k].z + v[k].w;
    sq += v[k].x * v[k].x + v[k].y * v[k].y + v[k].z * v[k].z + v[k].w * v[k].w;
  }
#pragma unroll
  for (int off = 32; off >= 1; off >>= 1) {
    s += __shfl_xor(s, off);
    sq += __shfl_xor(sq, off);
  }
  float mean = s * (1.f / 768.f);
  float rstd = rsqrtf(sq * (1.f / 768.f) - mean * mean + 1e-5f);
#pragma unroll
  for (int k = 0; k < 3; k++) {
    int c = (k * 64 + lane) * 4;
    float4 gg = *(const float4*)(g + c);
    float4 bb = *(const float4*)(b + c);
    bf16x4 pk = {(bf16)((v[k].x - mean) * rstd * gg.x + bb.x),
                 (bf16)((v[k].y - mean) * rstd * gg.y + bb.y),
                 (bf16)((v[k].z - mean) * rstd * gg.z + bb.z),
                 (bf16)((v[k].w - mean) * rstd * gg.w + bb.w)};
    *(bf16x4*)(h2 + row * 768 + c) = pk;
  }
}

// ------- ln3_reduce: t = gelu(p0+p1+b2)+x2(bf16); out = LN(t) f32 -------------
__global__ __launch_bounds__(256) void ln3_reduce_kernel(
    const bf16* __restrict__ p, const float* __restrict__ b2,
    const bf16* __restrict__ x2, const float* __restrict__ g,
    const float* __restrict__ b, float* __restrict__ out) {
  int w = threadIdx.x >> 6, lane = threadIdx.x & 63;
  size_t row = (size_t)blockIdx.x * 4 + w;
  const bf16* p0 = p + row * 768;
  const bf16* p1 = p0 + (size_t)M_TOK * 768;
  const bf16* xr = x2 + row * 768;
  float4 v[3];
  float s = 0.f, sq = 0.f;
#pragma unroll
  for (int k = 0; k < 3; k++) {
    int c = (k * 64 + lane) * 4;
    bf16x4 a0 = *(const bf16x4*)(p0 + c);
    bf16x4 a1 = *(const bf16x4*)(p1 + c);
    float4 bb = *(const float4*)(b2 + c);
    bf16x4 rr = *(const bf16x4*)(xr + c);
    v[k].x = gelu_f((float)a0[0] + (float)a1[0] + bb.x) + (float)rr[0];
    v[k].y = gelu_f((float)a0[1] + (float)a1[1] + bb.y) + (float)rr[1];
    v[k].z = gelu_f((float)a0[2] + (float)a1[2] + bb.z) + (float)rr[2];
    v[k].w = gelu_f((float)a0[3] + (float)a1[3] + bb.w) + (float)rr[3];
    s += v[k].x + v[k].y + v[k].z + v[k].w;
    sq += v[k].x * v[k].x + v[k].y * v[k].y + v[k].z * v[k].z + v[k].w * v[k].w;
  }
#pragma unroll
  for (int off = 32; off >= 1; off >>= 1) {
    s += __shfl_xor(s, off);
    sq += __shfl_xor(sq, off);
  }
  float mean = s * (1.f / 768.f);
  float rstd = rsqrtf(sq * (1.f / 768.f) - mean * mean + 1e-5f);
#pragma unroll
  for (int k = 0; k < 3; k++) {
    int c = (k * 64 + lane) * 4;
    float4 gg = *(const float4*)(g + c);
    float4 bb = *(const float4*)(b + c);
    float4 ov = {(v[k].x - mean) * rstd * gg.x + bb.x,
                 (v[k].y - mean) * rstd * gg.y + bb.y,
                 (v[k].z - mean) * rstd * gg.z + bb.z,
                 (v[k].w - mean) * rstd * gg.w + bb.w};
    *(float4*)(out + row * 768 + c) = ov;
  }
}

// ---------------- GEMM: C = A @ B^T, 128x128, 3 blocks/CU co-resident ---------
// ROUND-5: the R3/R4 cycle ledger showed ~3976 cyc/K-tile vs 1242 of MFMA with
// ONE resident block: all waves lockstep at the same lgkm/barrier -> CU idles.
// (LDS-BW theory of R4 was wrong: 512 B/MFMA = 105 B/cyc at FULL rate < port.)
// Fix = co-residency (m97/m114 mechanism): BK=32, 4 waves (2x2, 64x64/wave),
// TRIPLE-buffered 3x16KB = 48KB LDS -> 3 independent blocks/CU (12 waves,
// launch_bounds(256,3), ~120 VGPR). B through LDS (L2 demand ~14 TB/s, not
// R0's 28 which was L2-bound). Stage 2 tiles ahead, counted vmcnt(4) (never 0
// mid-loop, ~1.5 iters of latency cover), ONE barrier per K-tile, fences only
// where required (rule 18: sched_barrier after lgkmcnt(0)).
// A-tile [128 rows][4 chunks of 16B], XOR swizzle chunk^= (row>>1)&3 applied
// on the STAGING SOURCE (LDS linear) and on the read -> 2-way bank alias
// within 16-lane groups (free, m136). B fragment-linear (conflict-free).
// K order per output element identical to R3 (tile 2t/2t+1 == old k2=0/1).
template <int EPI, int LDA, int KTOT, int KSL, int NN>
__global__ __launch_bounds__(256, 3) void gemm128_kernel(
    const bf16* __restrict__ A, const bf16* __restrict__ Bf,
    const float* __restrict__ bias, bf16* __restrict__ outb,
    bf16* __restrict__ qo, bf16* __restrict__ ko, bf16* __restrict__ vto) {
  constexpr int KCg = KTOT / 32;   // B frag chunks per n16 row
  constexpr int NT = KSL / 32;     // K-tiles: 24 / 12 / 48 (all % 3 == 0)
  __shared__ __align__(16) bf16 smem[3][8192];  // per buf: A 8KB | B 8KB
  int tid = threadIdx.x;
  int w = tid >> 6, l = tid & 63;
  int qd = l >> 4, lr = l & 15;
  int bm0 = blockIdx.x * 128, bn0 = blockIdx.y * 128;
  int kb = blockIdx.z * KSL;
  int wm = (w >> 1) * 64, wn = (w & 1) * 64;
  int wnl = (w & 1) * 4;           // wave's first n16 frag

  // staging sources (per-lane; LDS dest wave-uniform + lane*16B linear)
  // A: lane covers row w*32 + g*16 + (l>>2), dest chunk (l&3); source chunk
  // pre-swizzled cs = (l&3) ^ ((l>>3)&3)  [== (l&3) ^ ((row>>1)&3)]
  const bf16* pA = A + (size_t)(bm0 + w * 32 + (l >> 2)) * LDA + kb +
                   (((l & 3) ^ ((l >> 3) & 3)) * 8);
  // B: wave w stages n16 chunks {2w, 2w+1}
  const bf16* pB =
      Bf + ((size_t)((bn0 >> 4) + w * 2) * KCg + (kb >> 5)) * 512 + l * 8;

  auto STG = [&](int t, int b) {  // stage full 16KB tile t into buf b
    char* dA = (char*)smem[b] + w * 2048;
    char* dB = (char*)smem[b] + 8192 + w * 2048;
    gld_lds16(pA + t * 32, dA);
    gld_lds16(pA + t * 32 + (size_t)16 * LDA, dA + 1024);
    gld_lds16(pB + (size_t)t * 512, dB);
    gld_lds16(pB + (size_t)KCg * 512 + (size_t)t * 512, dB + 1024);
  };
  auto LDF = [&](int b, bf16x8* af, bf16x8* bv) {
    const bf16* Ab = smem[b];
    const bf16* Bb = smem[b] + 4096;
#pragma unroll
    for (int i = 0; i < 4; ++i) {
      int r = wm + i * 16 + lr;
      af[i] = *(const bf16x8*)(Ab + r * 32 + ((qd ^ ((lr >> 1) & 3)) * 8));
    }
#pragma unroll
    for (int j = 0; j < 4; ++j)
      bv[j] = *(const bf16x8*)(Bb + (wnl + j) * 512 + l * 8);
  };

  f32x4 acc[4][4] = {};

  // prologue: tiles 0,1 staged; drain tile 0 (oldest 4), keep tile 1 in flight
  STG(0, 0);
  STG(1, 1);
  asm volatile("s_waitcnt vmcnt(4)" ::: "memory");
  __builtin_amdgcn_sched_barrier(0);
  __builtin_amdgcn_s_barrier();

#pragma unroll 1
  for (int t3 = 0; t3 < NT; t3 += 3) {
#pragma unroll
    for (int u = 0; u < 3; ++u) {
      const int t = t3 + u;
      const bool st = (t + 2) < NT;
      // stage 2 ahead into the buffer freed at the end of iter t-1
      if (st) STG(t + 2, (u + 2) % 3);
      __builtin_amdgcn_sched_barrier(0);
      bf16x8 af[4], bv[4];
      LDF(u, af, bv);
      asm volatile("s_waitcnt lgkmcnt(0)" ::: "memory");
      __builtin_amdgcn_sched_barrier(0);
      __builtin_amdgcn_s_setprio(1);
#pragma unroll
      for (int i = 0; i < 4; ++i)
#pragma unroll
        for (int j = 0; j < 4; ++j)
          acc[i][j] = __builtin_amdgcn_mfma_f32_16x16x32_bf16(
              af[i], bv[j], acc[i][j], 0, 0, 0);
      __builtin_amdgcn_s_setprio(0);
      if (t + 1 < NT) {
        // counted: tile t+1 landed; only tile t+2's 4 loads may stay in flight
        if (st) asm volatile("s_waitcnt vmcnt(4)" ::: "memory");
        else    asm volatile("s_waitcnt vmcnt(0)" ::: "memory");
        __builtin_amdgcn_sched_barrier(0);
        __builtin_amdgcn_s_barrier();
      }
    }
  }

  // ---- epilogue ----
  bf16* outbs = (EPI == 5) ? outb + (size_t)blockIdx.z * M_TOK * NN : outb;

#pragma unroll
  for (int i = 0; i < 4; i++) {
#pragma unroll
    for (int j = 0; j < 4; j++) {
      if (EPI == 4) {
        // fused qkv split (NN==2304). 16-col tiles never straddle head bounds.
        int colt = bn0 + wn + j * 16;
        int which = colt / 768;
        int rem = colt - which * 768;
        int h = rem / 96;
        int dhb = rem - h * 96;
        int row0 = bm0 + wm + i * 16 + qd * 4;
        int b = row0 >> 10, n0 = row0 & 1023;
        int bh = b * 8 + h;
        if (which == 2) {
          bf16x4 pk = {(bf16)acc[i][j][0], (bf16)acc[i][j][1],
                       (bf16)acc[i][j][2], (bf16)acc[i][j][3]};
          *(bf16x4*)(vto + ((size_t)(bh * 96 + dhb + lr)) * 1024 + n0) = pk;
        } else if (which == 0) {
          // q pre-scaled by 1/sqrt(dh) so attention skips the S-scale
#pragma unroll
          for (int r = 0; r < 4; r++)
            qo[((size_t)bh * 1024 + n0 + r) * 96 + dhb + lr] =
                (bf16)(acc[i][j][r] * SCALE_);
        } else {
#pragma unroll
          for (int r = 0; r < 4; r++)
            ko[((size_t)bh * 1024 + n0 + r) * 96 + dhb + lr] =
                (bf16)acc[i][j][r];
        }
      } else {
#pragma unroll
        for (int r = 0; r < 4; r++) {
          int row = bm0 + wm + i * 16 + qd * 4 + r;
          int col = bn0 + wn + j * 16 + lr;
          size_t o = (size_t)row * NN + col;
          float v = acc[i][j][r];
          if (EPI == 2) {
            outbs[o] = (bf16)gelu_f(v + bias[col]);
          } else {  // EPI == 5
            outbs[o] = (bf16)v;
          }
        }
      }
    }
  }
}

// ---------------- fused attention, 128 q-rows/block, 64-key tiles -------------
__global__ __launch_bounds__(256) void attn_kernel(
    const bf16* __restrict__ qb, const bf16* __restrict__ kb,
    const bf16* __restrict__ vtb, bf16* __restrict__ operm) {
  __shared__ __align__(16) bf16 Ks[2][64 * 104];   // [key][dh], pad 104
  __shared__ __align__(16) bf16 Vs[2][96 * 72];    // [dh][key], pad 72
  __shared__ __align__(16) bf16 Ps[128 * 72];      // [qrow][key], pad 72
  int t = threadIdx.x;
  int w = t >> 6, lane = t & 63;
  int qd = lane >> 4, lr = lane & 15;
  int bh = blockIdx.x, nt0 = blockIdx.y * 128;
  int bq = bh >> 3, hh = bh & 7;

  const bf16* kgb = kb + (size_t)bh * 1024 * 96;
  const bf16* vgb = vtb + (size_t)bh * 96 * 1024;

  bf16x8 kreg[3], vreg[3];
#pragma unroll
  for (int it = 0; it < 3; it++) {
    int idx = it * 256 + t;
    kreg[it] = *(const bf16x8*)(kgb + (idx / 12) * 96 + (idx % 12) * 8);
    vreg[it] = *(const bf16x8*)(vgb + (size_t)(idx >> 3) * 1024 + (idx & 7) * 8);
  }

  const bf16* qg = qb + ((size_t)bh * 1024 + nt0 + w * 32) * 96;
  bf16x8 afq[2][3];
#pragma unroll
  for (int i = 0; i < 2; i++)
#pragma unroll
    for (int ks = 0; ks < 3; ks++)
      afq[i][ks] = *(const bf16x8*)(qg + (i * 16 + lr) * 96 + ks * 32 + qd * 8);

  f32x4 oacc[2][6] = {};
  float lst[2][4] = {};

  int cur = 0;
  for (int kt = 0; kt < 16; kt++) {
#pragma unroll
    for (int it = 0; it < 3; it++) {
      int idx = it * 256 + t;
      *(bf16x8*)&Ks[cur][(idx / 12) * 104 + (idx % 12) * 8] = kreg[it];
      *(bf16x8*)&Vs[cur][(idx >> 3) * 72 + (idx & 7) * 8] = vreg[it];
    }
    if (kt < 15) {
      const bf16* kg = kgb + (size_t)(kt + 1) * 64 * 96;
      const bf16* vg = vgb + (kt + 1) * 64;
#pragma unroll
      for (int it = 0; it < 3; it++) {
        int idx = it * 256 + t;
        kreg[it] = *(const bf16x8*)(kg + (idx / 12) * 96 + (idx % 12) * 8);
        vreg[it] =
            *(const bf16x8*)(vg + (size_t)(idx >> 3) * 1024 + (idx & 7) * 8);
      }
    }
    __syncthreads();

    f32x4 sacc[2][4] = {};
#pragma unroll
    for (int ks = 0; ks < 3; ks++) {
      bf16x8 bk[4];
#pragma unroll
      for (int jn = 0; jn < 4; jn++)
        bk[jn] =
            *(const bf16x8*)&Ks[cur][(jn * 16 + lr) * 104 + ks * 32 + qd * 8];
#pragma unroll
      for (int i = 0; i < 2; i++)
#pragma unroll
        for (int jn = 0; jn < 4; jn++)
          sacc[i][jn] = __builtin_amdgcn_mfma_f32_16x16x32_bf16(
              afq[i][ks], bk[jn], sacc[i][jn], 0, 0, 0);
    }

#pragma unroll
    for (int i = 0; i < 2; i++)
#pragma unroll
      for (int jn = 0; jn < 4; jn++)
#pragma unroll
        for (int r = 0; r < 4; r++) {
          float p = __expf(sacc[i][jn][r]);
          lst[i][r] += p;
          Ps[(w * 32 + i * 16 + qd * 4 + r) * 72 + jn * 16 + lr] = (bf16)p;
        }

#pragma unroll
    for (int ks = 0; ks < 2; ks++) {
      bf16x8 ap[2];
#pragma unroll
      for (int i = 0; i < 2; i++)
        ap[i] =
            *(const bf16x8*)&Ps[(w * 32 + i * 16 + lr) * 72 + ks * 32 + qd * 8];
#pragma unroll
      for (int jn = 0; jn < 6; jn++) {
        bf16x8 bv =
            *(const bf16x8*)&Vs[cur][(jn * 16 + lr) * 72 + ks * 32 + qd * 8];
#pragma unroll
        for (int i = 0; i < 2; i++)
          oacc[i][jn] = __builtin_amdgcn_mfma_f32_16x16x32_bf16(
              ap[i], bv, oacc[i][jn], 0, 0, 0);
      }
    }
    cur ^= 1;
  }

#pragma unroll
  for (int i = 0; i < 2; i++)
#pragma unroll
    for (int r = 0; r < 4; r++) {
#pragma unroll
      for (int off = 1; off < 16; off <<= 1)
        lst[i][r] += __shfl_xor(lst[i][r], off);
    }

#pragma unroll
  for (int i = 0; i < 2; i++) {
#pragma unroll
    for (int r = 0; r < 4; r++) {
      float inv = 1.0f / lst[i][r];
      int n = nt0 + w * 32 + i * 16 + qd * 4 + r;
      size_t rowo = (size_t)bq * 1024 + hh * 128 + (n >> 3);
      int colb = 96 * (n & 7);
#pragma unroll
      for (int jn = 0; jn < 6; jn++)
        operm[rowo * 768 + colb + jn * 16 + lr] =
            (bf16)(oacc[i][jn][r] * inv);
    }
  }
}

// ------------------------------------------------------------------------------
extern "C" void kernel_launch(void* const* d_in, const int* in_sizes, int n_in,
                              void* d_out, int out_size, void* d_ws,
                              size_t ws_size, hipStream_t stream) {
  const float* x = (const float*)d_in[0];
  const float* w_qkv = (const float*)d_in[1];
  const float* w_o = (const float*)d_in[2];
  const float* b_o = (const float*)d_in[3];
  const float* w1 = (const float*)d_in[4];
  const float* b1 = (const float*)d_in[5];
  const float* w2 = (const float*)d_in[6];
  const float* b2 = (const float*)d_in[7];
  const float* g1 = (const float*)d_in[8];
  const float* be1 = (const float*)d_in[9];
  const float* gm = (const float*)d_in[10];
  const float* bm = (const float*)d_in[11];
  const float* g3 = (const float*)d_in[12];
  const float* be3 = (const float*)d_in[13];

  char* ws = (char*)d_ws;
  size_t off = 0;
  auto alloc = [&](size_t bytes) {
    char* p = ws + off;
    off += (bytes + 255) & ~(size_t)255;
    return p;
  };
  const size_t SZ_TOK_BF = (size_t)M_TOK * 768 * 2;   // 12.58 MB
  bf16* fqkv = (bf16*)alloc((size_t)2304 * 768 * 2);
  bf16* fwo = (bf16*)alloc((size_t)768 * 768 * 2);
  bf16* fw1 = (bf16*)alloc((size_t)3072 * 768 * 2);
  bf16* fw2 = (bf16*)alloc((size_t)768 * 3072 * 2);
  bf16* hA = (bf16*)alloc(SZ_TOK_BF);   // LN1 out; then operm; then h2
  bf16* qb = (bf16*)alloc(SZ_TOK_BF);
  bf16* kbuf = (bf16*)alloc(SZ_TOK_BF);
  bf16* vtb = (bf16*)alloc(SZ_TOK_BF);
  bf16* x2 = (bf16*)alloc(SZ_TOK_BF);
  char* G = alloc((size_t)M_TOK * 3072 * 2);
  bf16* operm = hA;
  bf16* h2 = hA;
  bf16* pWo = (bf16*)G;
  bf16* a1 = (bf16*)G;
  bf16* pW2 = hA;  // spans hA+qb (2 x 12.58 MB), live after a1's last read

  make_frags_kernel<<<3456, 256, 0, stream>>>(w_qkv, w_o, w1, w2, fqkv, fwo,
                                              fw1, fw2);

  ln_kernel<<<M_TOK / 4, 256, 0, stream>>>(x, g1, be1, hA);

  // QKV GEMM with fused head-split epilogue (q pre-scaled by 1/sqrt(dh))
  gemm128_kernel<4, 768, 768, 768, 2304><<<dim3(64, 18), 256, 0, stream>>>(
      hA, fqkv, nullptr, nullptr, qb, kbuf, vtb);

  attn_kernel<<<dim3(64, 8), 256, 0, stream>>>(qb, kbuf, vtb, operm);

  // Wo GEMM, split-K=2 (slices of 384) -> bf16 partials in G
  gemm128_kernel<5, 768, 768, 384, 768><<<dim3(64, 6, 2), 256, 0, stream>>>(
      operm, fwo, nullptr, pWo, nullptr, nullptr, nullptr);

  ln2_reduce_kernel<<<M_TOK / 4, 256, 0, stream>>>(pWo, b_o, x, gm, bm, x2, h2);

  // W1 GEMM: bias + GELU -> bf16 a1
  gemm128_kernel<2, 768, 768, 768, 3072><<<dim3(64, 24), 256, 0, stream>>>(
      h2, fw1, b1, a1, nullptr, nullptr, nullptr);

  // W2 GEMM, split-K=2 (slices of 1536) -> bf16 partials spanning hA+qb
  gemm128_kernel<5, 3072, 3072, 1536, 768><<<dim3(64, 6, 2), 256, 0, stream>>>(
      a1, fw2, nullptr, pW2, nullptr, nullptr, nullptr);

  ln3_reduce_kernel<<<M_TOK / 4, 256, 0, stream>>>(pW2, b2, x2, g3, be3,
                                                   (float*)d_out);
}

// Round 6
// 323.631 us; speedup vs baseline: 1.1062x; 1.0009x over previous
//
#include <hip/hip_runtime.h>
#include <cmath>
#include <cstdint>

typedef __bf16 bf16;
typedef __bf16 bf16x8 __attribute__((ext_vector_type(8)));
typedef __bf16 bf16x4 __attribute__((ext_vector_type(4)));
typedef float  f32x4  __attribute__((ext_vector_type(4)));

#define M_TOK 8192
#define SCALE_ 0.10206207261596575f   // 96^-0.5

__device__ __forceinline__ void gld_lds16(const void* g, void* l) {
  __builtin_amdgcn_global_load_lds(
      (__attribute__((address_space(1))) void*)(uintptr_t)g,
      (__attribute__((address_space(3))) void*)(uintptr_t)l,
      16, 0, 0);
}

// tanh-approx GELU (max |err| vs exact ~3e-3); tanh via v_exp_f32
__device__ __forceinline__ float gelu_f(float x) {
  float u = x * (0.7978845608f + 0.0356774081f * x * x);
  float t = 1.0f - 2.0f / (__expf(2.0f * u) + 1.0f);
  return 0.5f * x * (1.0f + t);
}

// ------- weight -> MFMA-fragment layout (B-operand order), all 4 weights -----
__global__ __launch_bounds__(256) void make_frags_kernel(
    const float* __restrict__ w_qkv, const float* __restrict__ w_o,
    const float* __restrict__ w1, const float* __restrict__ w2,
    bf16* __restrict__ fqkv, bf16* __restrict__ fwo, bf16* __restrict__ fw1,
    bf16* __restrict__ fw2) {
  int chunk = blockIdx.x * 4 + (threadIdx.x >> 6);
  int lane = threadIdx.x & 63;
  const float* src;
  bf16* dst;
  int K, N, base;
  if (chunk < 3456) {
    src = w_qkv; dst = fqkv; K = 768; N = 2304; base = 0;
  } else if (chunk < 4608) {
    src = w_o; dst = fwo; K = 768; N = 768; base = 3456;
  } else if (chunk < 9216) {
    src = w1; dst = fw1; K = 768; N = 3072; base = 4608;
  } else {
    src = w2; dst = fw2; K = 3072; N = 768; base = 9216;
  }
  int lid = chunk - base;
  int kc = K / 32;
  int n16 = lid / kc, c = lid - n16 * kc;
  int lr = lane & 15, qd = lane >> 4;
  int n = n16 * 16 + lr;
  int k0 = c * 32 + qd * 8;
  bf16x8 v;
#pragma unroll
  for (int e = 0; e < 8; e++) v[e] = (bf16)src[(size_t)(k0 + e) * N + n];
  *(bf16x8*)&dst[(size_t)lid * 512 + lane * 8] = v;
}

// ---------------- layernorm (f32 in -> bf16 out), one wave per row ------------
__global__ __launch_bounds__(256) void ln_kernel(
    const float* __restrict__ x, const float* __restrict__ g,
    const float* __restrict__ b, bf16* __restrict__ ob) {
  int w = threadIdx.x >> 6, lane = threadIdx.x & 63;
  size_t row = (size_t)blockIdx.x * 4 + w;
  const float* xr = x + row * 768;
  float4 v[3];
  float s = 0.f, sq = 0.f;
#pragma unroll
  for (int k = 0; k < 3; k++) {
    v[k] = *(const float4*)(xr + (k * 64 + lane) * 4);
    s += v[k].x + v[k].y + v[k].z + v[k].w;
    sq += v[k].x * v[k].x + v[k].y * v[k].y + v[k].z * v[k].z + v[k].w * v[k].w;
  }
#pragma unroll
  for (int off = 32; off >= 1; off >>= 1) {
    s += __shfl_xor(s, off);
    sq += __shfl_xor(sq, off);
  }
  float mean = s * (1.f / 768.f);
  float rstd = rsqrtf(sq * (1.f / 768.f) - mean * mean + 1e-5f);
#pragma unroll
  for (int k = 0; k < 3; k++) {
    int c = (k * 64 + lane) * 4;
    float4 gg = *(const float4*)(g + c);
    float4 bb = *(const float4*)(b + c);
    bf16x4 pk = {(bf16)((v[k].x - mean) * rstd * gg.x + bb.x),
                 (bf16)((v[k].y - mean) * rstd * gg.y + bb.y),
                 (bf16)((v[k].z - mean) * rstd * gg.z + bb.z),
                 (bf16)((v[k].w - mean) * rstd * gg.w + bb.w)};
    *(bf16x4*)(ob + row * 768 + c) = pk;
  }
}

// ------- ln2_reduce: t = p0+p1+b_o+x(resid f32); x2=t (bf16); h2 = LN(t) bf16 -
__global__ __launch_bounds__(256) void ln2_reduce_kernel(
    const bf16* __restrict__ p, const float* __restrict__ bo,
    const float* __restrict__ xres, const float* __restrict__ g,
    const float* __restrict__ b, bf16* __restrict__ x2,
    bf16* __restrict__ h2) {
  int w = threadIdx.x >> 6, lane = threadIdx.x & 63;
  size_t row = (size_t)blockIdx.x * 4 + w;
  const bf16* p0 = p + row * 768;
  const bf16* p1 = p0 + (size_t)M_TOK * 768;
  const float* xr = xres + row * 768;
  float4 v[3];
  float s = 0.f, sq = 0.f;
#pragma unroll
  for (int k = 0; k < 3; k++) {
    int c = (k * 64 + lane) * 4;
    bf16x4 a0 = *(const bf16x4*)(p0 + c);
    bf16x4 a1 = *(const bf16x4*)(p1 + c);
    float4 bb = *(const float4*)(bo + c);
    float4 rr = *(const float4*)(xr + c);
    v[k].x = (float)a0[0] + (float)a1[0] + bb.x + rr.x;
    v[k].y = (float)a0[1] + (float)a1[1] + bb.y + rr.y;
    v[k].z = (float)a0[2] + (float)a1[2] + bb.z + rr.z;
    v[k].w = (float)a0[3] + (float)a1[3] + bb.w + rr.w;
    bf16x4 xo = {(bf16)v[k].x, (bf16)v[k].y, (bf16)v[k].z, (bf16)v[k].w};
    *(bf16x4*)(x2 + row * 768 + c) = xo;
    s += v[k].x + v[k].y + v[k].z + v[k].w;
    sq += v[k].x * v[k].x + v[k].y * v[k].y + v[k].z * v[k].z + v[k].w * v[k].w;
  }
#pragma unroll
  for (int off = 32; off >= 1; off >>= 1) {
    s += __shfl_xor(s, off);
    sq += __shfl_xor(sq, off);
  }
  float mean = s * (1.f / 768.f);
  float rstd = rsqrtf(sq * (1.f / 768.f) - mean * mean + 1e-5f);
#pragma unroll
  for (int k = 0; k < 3; k++) {
    int c = (k * 64 + lane) * 4;
    float4 gg = *(const float4*)(g + c);
    float4 bb = *(const float4*)(b + c);
    bf16x4 pk = {(bf16)((v[k].x - mean) * rstd * gg.x + bb.x),
                 (bf16)((v[k].y - mean) * rstd * gg.y + bb.y),
                 (bf16)((v[k].z - mean) * rstd * gg.z + bb.z),
                 (bf16)((v[k].w - mean) * rstd * gg.w + bb.w)};
    *(bf16x4*)(h2 + row * 768 + c) = pk;
  }
}

// ------- ln3_reduce: t = gelu(p0+p1+b2)+x2(bf16); out = LN(t) f32 -------------
__global__ __launch_bounds__(256) void ln3_reduce_kernel(
    const bf16* __restrict__ p, const float* __restrict__ b2,
    const bf16* __restrict__ x2, const float* __restrict__ g,
    const float* __restrict__ b, float* __restrict__ out) {
  int w = threadIdx.x >> 6, lane = threadIdx.x & 63;
  size_t row = (size_t)blockIdx.x * 4 + w;
  const bf16* p0 = p + row * 768;
  const bf16* p1 = p0 + (size_t)M_TOK * 768;
  const bf16* xr = x2 + row * 768;
  float4 v[3];
  float s = 0.f, sq = 0.f;
#pragma unroll
  for (int k = 0; k < 3; k++) {
    int c = (k * 64 + lane) * 4;
    bf16x4 a0 = *(const bf16x4*)(p0 + c);
    bf16x4 a1 = *(const bf16x4*)(p1 + c);
    float4 bb = *(const float4*)(b2 + c);
    bf16x4 rr = *(const bf16x4*)(xr + c);
    v[k].x = gelu_f((float)a0[0] + (float)a1[0] + bb.x) + (float)rr[0];
    v[k].y = gelu_f((float)a0[1] + (float)a1[1] + bb.y) + (float)rr[1];
    v[k].z = gelu_f((float)a0[2] + (float)a1[2] + bb.z) + (float)rr[2];
    v[k].w = gelu_f((float)a0[3] + (float)a1[3] + bb.w) + (float)rr[3];
    s += v[k].x + v[k].y + v[k].z + v[k].w;
    sq += v[k].x * v[k].x + v[k].y * v[k].y + v[k].z * v[k].z + v[k].w * v[k].w;
  }
#pragma unroll
  for (int off = 32; off >= 1; off >>= 1) {
    s += __shfl_xor(s, off);
    sq += __shfl_xor(sq, off);
  }
  float mean = s * (1.f / 768.f);
  float rstd = rsqrtf(sq * (1.f / 768.f) - mean * mean + 1e-5f);
#pragma unroll
  for (int k = 0; k < 3; k++) {
    int c = (k * 64 + lane) * 4;
    float4 gg = *(const float4*)(g + c);
    float4 bb = *(const float4*)(b + c);
    float4 ov = {(v[k].x - mean) * rstd * gg.x + bb.x,
                 (v[k].y - mean) * rstd * gg.y + bb.y,
                 (v[k].z - mean) * rstd * gg.z + bb.z,
                 (v[k].w - mean) * rstd * gg.w + bb.w};
    *(float4*)(out + row * 768 + c) = ov;
  }
}

// ---------------- GEMM: C = A @ B^T, 128x128, co-resident + reg pipeline ------
// ROUND-6 = R5 (3 blocks/CU, BK=32, 3x16KB bufs) + one-ahead register pipeline
// (R3 mechanism): reads for tile t+1 issue BEFORE tile t's MFMA cluster and
// are waited only one cluster later (lgkmcnt(8)) -> ds_read latency fully
// hidden. Per iter:
//   STG(t+2) ; vmcnt(4) [per-wave gate: OWN staging of t+1 landed] ;
//   barrier#1 [ALL waves' t+1 staging gated -> LDS tile t+1 complete] ;
//   LDF(t+1 -> setR) ; lgkmcnt(8) [setM ready, setR in flight] ;
//   setprio(1) 16xMFMA(setM) setprio(0) ;
//   barrier#2 [reads of t-1 (lgkm'd before this point in iter t-1... ) --
//              formally: lgkm-wait(setM=t) < bar#2(t) < STG(t+2) of iter t+1;
//              so buffer (t+2)%3's last reads (tile t-1, completed at iter
//              t-1's lgkm(8)) precede bar#2(t-1) < its overwrite at iter t]
// Counted vmcnt never 0 mid-loop. Fragment sets alternate with compile-time
// parity (6-unroll; NT = 24/12/48 all % 6 == 0). Geometry/swizzle == R5
// (0 bank conflicts measured). K order per output element unchanged.
template <int EPI, int LDA, int KTOT, int KSL, int NN>
__global__ __launch_bounds__(256, 3) void gemm128_kernel(
    const bf16* __restrict__ A, const bf16* __restrict__ Bf,
    const float* __restrict__ bias, bf16* __restrict__ outb,
    bf16* __restrict__ qo, bf16* __restrict__ ko, bf16* __restrict__ vto) {
  constexpr int KCg = KTOT / 32;   // B frag chunks per n16 row
  constexpr int NT = KSL / 32;     // K-tiles: 24 / 12 / 48 (all % 6 == 0)
  __shared__ __align__(16) bf16 smem[3][8192];  // per buf: A 8KB | B 8KB
  int tid = threadIdx.x;
  int w = tid >> 6, l = tid & 63;
  int qd = l >> 4, lr = l & 15;
  int bm0 = blockIdx.x * 128, bn0 = blockIdx.y * 128;
  int kb = blockIdx.z * KSL;
  int wm = (w >> 1) * 64, wn = (w & 1) * 64;
  int wnl = (w & 1) * 4;           // wave's first n16 frag

  // staging sources (per-lane; LDS dest wave-uniform + lane*16B linear)
  const bf16* pA = A + (size_t)(bm0 + w * 32 + (l >> 2)) * LDA + kb +
                   (((l & 3) ^ ((l >> 3) & 3)) * 8);
  const bf16* pB =
      Bf + ((size_t)((bn0 >> 4) + w * 2) * KCg + (kb >> 5)) * 512 + l * 8;

  auto STG = [&](int t, int b) {  // stage full 16KB tile t into buf b
    char* dA = (char*)smem[b] + w * 2048;
    char* dB = (char*)smem[b] + 8192 + w * 2048;
    gld_lds16(pA + t * 32, dA);
    gld_lds16(pA + t * 32 + (size_t)16 * LDA, dA + 1024);
    gld_lds16(pB + (size_t)t * 512, dB);
    gld_lds16(pB + (size_t)KCg * 512 + (size_t)t * 512, dB + 1024);
  };
  auto LDF = [&](int b, bf16x8* af, bf16x8* bv) {
    const bf16* Ab = smem[b];
    const bf16* Bb = smem[b] + 4096;
#pragma unroll
    for (int i = 0; i < 4; ++i) {
      int r = wm + i * 16 + lr;
      af[i] = *(const bf16x8*)(Ab + r * 32 + ((qd ^ ((lr >> 1) & 3)) * 8));
    }
#pragma unroll
    for (int j = 0; j < 4; ++j)
      bv[j] = *(const bf16x8*)(Bb + (wnl + j) * 512 + l * 8);
  };

  f32x4 acc[4][4] = {};
  auto MM = [&](bf16x8* af, bf16x8* bv) {
#pragma unroll
    for (int i = 0; i < 4; ++i)
#pragma unroll
      for (int j = 0; j < 4; ++j)
        acc[i][j] = __builtin_amdgcn_mfma_f32_16x16x32_bf16(
            af[i], bv[j], acc[i][j], 0, 0, 0);
  };

  // prologue: tiles 0,1 staged; tile 0 drained+barrier'd; tile0 frags -> set A
  STG(0, 0);
  STG(1, 1);
  asm volatile("s_waitcnt vmcnt(4)" ::: "memory");
  __builtin_amdgcn_sched_barrier(0);
  __builtin_amdgcn_s_barrier();
  __builtin_amdgcn_sched_barrier(0);
  bf16x8 aA[4], bA[4], aB[4], bB[4];
  LDF(0, aA, bA);
  __builtin_amdgcn_sched_barrier(0);

#pragma unroll 1
  for (int t6 = 0; t6 < NT; t6 += 6) {
#pragma unroll
    for (int v = 0; v < 6; ++v) {
      const int t = t6 + v;
      const int u = v % 3;                 // == t % 3 (t6 % 6 == 0)
      const bool rd = (t + 1) < NT;
      const bool st = (t + 2) < NT;
      bf16x8* afM = (v & 1) ? aB : aA;
      bf16x8* bvM = (v & 1) ? bB : bA;
      bf16x8* afR = (v & 1) ? aA : aB;
      bf16x8* bvR = (v & 1) ? bA : bB;

      if (st) STG(t + 2, (u + 2) % 3);
      __builtin_amdgcn_sched_barrier(0);
      if (rd) {
        // per-wave gate: own staging of tile t+1 landed (t+2's may fly)
        if (st) asm volatile("s_waitcnt vmcnt(4)" ::: "memory");
        else    asm volatile("s_waitcnt vmcnt(0)" ::: "memory");
        __builtin_amdgcn_sched_barrier(0);
        __builtin_amdgcn_s_barrier();      // all waves gated -> t+1 complete
        __builtin_amdgcn_sched_barrier(0);
        LDF((u + 1) % 3, afR, bvR);        // reads hide under MFMA below
        asm volatile("s_waitcnt lgkmcnt(8)" ::: "memory");  // setM ready
      } else {
        asm volatile("s_waitcnt lgkmcnt(0)" ::: "memory");
      }
      __builtin_amdgcn_sched_barrier(0);
      __builtin_amdgcn_s_setprio(1);
      MM(afM, bvM);
      __builtin_amdgcn_s_setprio(0);
      __builtin_amdgcn_sched_barrier(0);
      if (rd) __builtin_amdgcn_s_barrier();  // protects buffer re-staging
    }
  }

  // ---- epilogue ----
  bf16* outbs = (EPI == 5) ? outb + (size_t)blockIdx.z * M_TOK * NN : outb;

#pragma unroll
  for (int i = 0; i < 4; i++) {
#pragma unroll
    for (int j = 0; j < 4; j++) {
      if (EPI == 4) {
        // fused qkv split (NN==2304). 16-col tiles never straddle head bounds.
        int colt = bn0 + wn + j * 16;
        int which = colt / 768;
        int rem = colt - which * 768;
        int h = rem / 96;
        int dhb = rem - h * 96;
        int row0 = bm0 + wm + i * 16 + qd * 4;
        int b = row0 >> 10, n0 = row0 & 1023;
        int bh = b * 8 + h;
        if (which == 2) {
          bf16x4 pk = {(bf16)acc[i][j][0], (bf16)acc[i][j][1],
                       (bf16)acc[i][j][2], (bf16)acc[i][j][3]};
          *(bf16x4*)(vto + ((size_t)(bh * 96 + dhb + lr)) * 1024 + n0) = pk;
        } else if (which == 0) {
          // q pre-scaled by 1/sqrt(dh) so attention skips the S-scale
#pragma unroll
          for (int r = 0; r < 4; r++)
            qo[((size_t)bh * 1024 + n0 + r) * 96 + dhb + lr] =
                (bf16)(acc[i][j][r] * SCALE_);
        } else {
#pragma unroll
          for (int r = 0; r < 4; r++)
            ko[((size_t)bh * 1024 + n0 + r) * 96 + dhb + lr] =
                (bf16)acc[i][j][r];
        }
      } else {
#pragma unroll
        for (int r = 0; r < 4; r++) {
          int row = bm0 + wm + i * 16 + qd * 4 + r;
          int col = bn0 + wn + j * 16 + lr;
          size_t o = (size_t)row * NN + col;
          float v = acc[i][j][r];
          if (EPI == 2) {
            outbs[o] = (bf16)gelu_f(v + bias[col]);
          } else {  // EPI == 5
            outbs[o] = (bf16)v;
          }
        }
      }
    }
  }
}

// ---------------- fused attention, 128 q-rows/block, 64-key tiles -------------
__global__ __launch_bounds__(256) void attn_kernel(
    const bf16* __restrict__ qb, const bf16* __restrict__ kb,
    const bf16* __restrict__ vtb, bf16* __restrict__ operm) {
  __shared__ __align__(16) bf16 Ks[2][64 * 104];   // [key][dh], pad 104
  __shared__ __align__(16) bf16 Vs[2][96 * 72];    // [dh][key], pad 72
  __shared__ __align__(16) bf16 Ps[128 * 72];      // [qrow][key], pad 72
  int t = threadIdx.x;
  int w = t >> 6, lane = t & 63;
  int qd = lane >> 4, lr = lane & 15;
  int bh = blockIdx.x, nt0 = blockIdx.y * 128;
  int bq = bh >> 3, hh = bh & 7;

  const bf16* kgb = kb + (size_t)bh * 1024 * 96;
  const bf16* vgb = vtb + (size_t)bh * 96 * 1024;

  bf16x8 kreg[3], vreg[3];
#pragma unroll
  for (int it = 0; it < 3; it++) {
    int idx = it * 256 + t;
    kreg[it] = *(const bf16x8*)(kgb + (idx / 12) * 96 + (idx % 12) * 8);
    vreg[it] = *(const bf16x8*)(vgb + (size_t)(idx >> 3) * 1024 + (idx & 7) * 8);
  }

  const bf16* qg = qb + ((size_t)bh * 1024 + nt0 + w * 32) * 96;
  bf16x8 afq[2][3];
#pragma unroll
  for (int i = 0; i < 2; i++)
#pragma unroll
    for (int ks = 0; ks < 3; ks++)
      afq[i][ks] = *(const bf16x8*)(qg + (i * 16 + lr) * 96 + ks * 32 + qd * 8);

  f32x4 oacc[2][6] = {};
  float lst[2][4] = {};

  int cur = 0;
  for (int kt = 0; kt < 16; kt++) {
#pragma unroll
    for (int it = 0; it < 3; it++) {
      int idx = it * 256 + t;
      *(bf16x8*)&Ks[cur][(idx / 12) * 104 + (idx % 12) * 8] = kreg[it];
      *(bf16x8*)&Vs[cur][(idx >> 3) * 72 + (idx & 7) * 8] = vreg[it];
    }
    if (kt < 15) {
      const bf16* kg = kgb + (size_t)(kt + 1) * 64 * 96;
      const bf16* vg = vgb + (kt + 1) * 64;
#pragma unroll
      for (int it = 0; it < 3; it++) {
        int idx = it * 256 + t;
        kreg[it] = *(const bf16x8*)(kg + (idx / 12) * 96 + (idx % 12) * 8);
        vreg[it] =
            *(const bf16x8*)(vg + (size_t)(idx >> 3) * 1024 + (idx & 7) * 8);
      }
    }
    __syncthreads();

    f32x4 sacc[2][4] = {};
#pragma unroll
    for (int ks = 0; ks < 3; ks++) {
      bf16x8 bk[4];
#pragma unroll
      for (int jn = 0; jn < 4; jn++)
        bk[jn] =
            *(const bf16x8*)&Ks[cur][(jn * 16 + lr) * 104 + ks * 32 + qd * 8];
#pragma unroll
      for (int i = 0; i < 2; i++)
#pragma unroll
        for (int jn = 0; jn < 4; jn++)
          sacc[i][jn] = __builtin_amdgcn_mfma_f32_16x16x32_bf16(
              afq[i][ks], bk[jn], sacc[i][jn], 0, 0, 0);
    }

#pragma unroll
    for (int i = 0; i < 2; i++)
#pragma unroll
      for (int jn = 0; jn < 4; jn++)
#pragma unroll
        for (int r = 0; r < 4; r++) {
          float p = __expf(sacc[i][jn][r]);
          lst[i][r] += p;
          Ps[(w * 32 + i * 16 + qd * 4 + r) * 72 + jn * 16 + lr] = (bf16)p;
        }

#pragma unroll
    for (int ks = 0; ks < 2; ks++) {
      bf16x8 ap[2];
#pragma unroll
      for (int i = 0; i < 2; i++)
        ap[i] =
            *(const bf16x8*)&Ps[(w * 32 + i * 16 + lr) * 72 + ks * 32 + qd * 8];
#pragma unroll
      for (int jn = 0; jn < 6; jn++) {
        bf16x8 bv =
            *(const bf16x8*)&Vs[cur][(jn * 16 + lr) * 72 + ks * 32 + qd * 8];
#pragma unroll
        for (int i = 0; i < 2; i++)
          oacc[i][jn] = __builtin_amdgcn_mfma_f32_16x16x32_bf16(
              ap[i], bv, oacc[i][jn], 0, 0, 0);
      }
    }
    cur ^= 1;
  }

#pragma unroll
  for (int i = 0; i < 2; i++)
#pragma unroll
    for (int r = 0; r < 4; r++) {
#pragma unroll
      for (int off = 1; off < 16; off <<= 1)
        lst[i][r] += __shfl_xor(lst[i][r], off);
    }

#pragma unroll
  for (int i = 0; i < 2; i++) {
#pragma unroll
    for (int r = 0; r < 4; r++) {
      float inv = 1.0f / lst[i][r];
      int n = nt0 + w * 32 + i * 16 + qd * 4 + r;
      size_t rowo = (size_t)bq * 1024 + hh * 128 + (n >> 3);
      int colb = 96 * (n & 7);
#pragma unroll
      for (int jn = 0; jn < 6; jn++)
        operm[rowo * 768 + colb + jn * 16 + lr] =
            (bf16)(oacc[i][jn][r] * inv);
    }
  }
}

// ------------------------------------------------------------------------------
extern "C" void kernel_launch(void* const* d_in, const int* in_sizes, int n_in,
                              void* d_out, int out_size, void* d_ws,
                              size_t ws_size, hipStream_t stream) {
  const float* x = (const float*)d_in[0];
  const float* w_qkv = (const float*)d_in[1];
  const float* w_o = (const float*)d_in[2];
  const float* b_o = (const float*)d_in[3];
  const float* w1 = (const float*)d_in[4];
  const float* b1 = (const float*)d_in[5];
  const float* w2 = (const float*)d_in[6];
  const float* b2 = (const float*)d_in[7];
  const float* g1 = (const float*)d_in[8];
  const float* be1 = (const float*)d_in[9];
  const float* gm = (const float*)d_in[10];
  const float* bm = (const float*)d_in[11];
  const float* g3 = (const float*)d_in[12];
  const float* be3 = (const float*)d_in[13];

  char* ws = (char*)d_ws;
  size_t off = 0;
  auto alloc = [&](size_t bytes) {
    char* p = ws + off;
    off += (bytes + 255) & ~(size_t)255;
    return p;
  };
  const size_t SZ_TOK_BF = (size_t)M_TOK * 768 * 2;   // 12.58 MB
  bf16* fqkv = (bf16*)alloc((size_t)2304 * 768 * 2);
  bf16* fwo = (bf16*)alloc((size_t)768 * 768 * 2);
  bf16* fw1 = (bf16*)alloc((size_t)3072 * 768 * 2);
  bf16* fw2 = (bf16*)alloc((size_t)768 * 3072 * 2);
  bf16* hA = (bf16*)alloc(SZ_TOK_BF);   // LN1 out; then operm; then h2
  bf16* qb = (bf16*)alloc(SZ_TOK_BF);
  bf16* kbuf = (bf16*)alloc(SZ_TOK_BF);
  bf16* vtb = (bf16*)alloc(SZ_TOK_BF);
  bf16* x2 = (bf16*)alloc(SZ_TOK_BF);
  char* G = alloc((size_t)M_TOK * 3072 * 2);
  bf16* operm = hA;
  bf16* h2 = hA;
  bf16* pWo = (bf16*)G;
  bf16* a1 = (bf16*)G;
  bf16* pW2 = hA;  // spans hA+qb (2 x 12.58 MB), live after a1's last read

  make_frags_kernel<<<3456, 256, 0, stream>>>(w_qkv, w_o, w1, w2, fqkv, fwo,
                                              fw1, fw2);

  ln_kernel<<<M_TOK / 4, 256, 0, stream>>>(x, g1, be1, hA);

  // QKV GEMM with fused head-split epilogue (q pre-scaled by 1/sqrt(dh))
  gemm128_kernel<4, 768, 768, 768, 2304><<<dim3(64, 18), 256, 0, stream>>>(
      hA, fqkv, nullptr, nullptr, qb, kbuf, vtb);

  attn_kernel<<<dim3(64, 8), 256, 0, stream>>>(qb, kbuf, vtb, operm);

  // Wo GEMM, split-K=2 (slices of 384) -> bf16 partials in G
  gemm128_kernel<5, 768, 768, 384, 768><<<dim3(64, 6, 2), 256, 0, stream>>>(
      operm, fwo, nullptr, pWo, nullptr, nullptr, nullptr);

  ln2_reduce_kernel<<<M_TOK / 4, 256, 0, stream>>>(pWo, b_o, x, gm, bm, x2, h2);

  // W1 GEMM: bias + GELU -> bf16 a1
  gemm128_kernel<2, 768, 768, 768, 3072><<<dim3(64, 24), 256, 0, stream>>>(
      h2, fw1, b1, a1, nullptr, nullptr, nullptr);

  // W2 GEMM, split-K=2 (slices of 1536) -> bf16 partials spanning hA+qb
  gemm128_kernel<5, 3072, 3072, 1536, 768><<<dim3(64, 6, 2), 256, 0, stream>>>(
      a1, fw2, nullptr, pW2, nullptr, nullptr, nullptr);

  ln3_reduce_kernel<<<M_TOK / 4, 256, 0, stream>>>(pW2, b2, x2, g3, be3,
                                                   (float*)d_out);
}

// Round 7
// 321.045 us; speedup vs baseline: 1.1151x; 1.0081x over previous
//
#include <hip/hip_runtime.h>
#include <cmath>
#include <cstdint>

typedef __bf16 bf16;
typedef __bf16 bf16x8 __attribute__((ext_vector_type(8)));
typedef __bf16 bf16x4 __attribute__((ext_vector_type(4)));
typedef float  f32x4  __attribute__((ext_vector_type(4)));

#define M_TOK 8192
#define SCALE_ 0.10206207261596575f   // 96^-0.5

__device__ __forceinline__ void gld_lds16(const void* g, void* l) {
  __builtin_amdgcn_global_load_lds(
      (__attribute__((address_space(1))) void*)(uintptr_t)g,
      (__attribute__((address_space(3))) void*)(uintptr_t)l,
      16, 0, 0);
}

// tanh-approx GELU (max |err| vs exact ~3e-3); tanh via v_exp_f32
__device__ __forceinline__ float gelu_f(float x) {
  float u = x * (0.7978845608f + 0.0356774081f * x * x);
  float t = 1.0f - 2.0f / (__expf(2.0f * u) + 1.0f);
  return 0.5f * x * (1.0f + t);
}

// ------- weight -> MFMA-fragment layout (B-operand order), all 4 weights -----
__global__ __launch_bounds__(256) void make_frags_kernel(
    const float* __restrict__ w_qkv, const float* __restrict__ w_o,
    const float* __restrict__ w1, const float* __restrict__ w2,
    bf16* __restrict__ fqkv, bf16* __restrict__ fwo, bf16* __restrict__ fw1,
    bf16* __restrict__ fw2) {
  int chunk = blockIdx.x * 4 + (threadIdx.x >> 6);
  int lane = threadIdx.x & 63;
  const float* src;
  bf16* dst;
  int K, N, base;
  if (chunk < 3456) {
    src = w_qkv; dst = fqkv; K = 768; N = 2304; base = 0;
  } else if (chunk < 4608) {
    src = w_o; dst = fwo; K = 768; N = 768; base = 3456;
  } else if (chunk < 9216) {
    src = w1; dst = fw1; K = 768; N = 3072; base = 4608;
  } else {
    src = w2; dst = fw2; K = 3072; N = 768; base = 9216;
  }
  int lid = chunk - base;
  int kc = K / 32;
  int n16 = lid / kc, c = lid - n16 * kc;
  int lr = lane & 15, qd = lane >> 4;
  int n = n16 * 16 + lr;
  int k0 = c * 32 + qd * 8;
  bf16x8 v;
#pragma unroll
  for (int e = 0; e < 8; e++) v[e] = (bf16)src[(size_t)(k0 + e) * N + n];
  *(bf16x8*)&dst[(size_t)lid * 512 + lane * 8] = v;
}

// ---------------- layernorm (f32 in -> bf16 out), one wave per row ------------
__global__ __launch_bounds__(256) void ln_kernel(
    const float* __restrict__ x, const float* __restrict__ g,
    const float* __restrict__ b, bf16* __restrict__ ob) {
  int w = threadIdx.x >> 6, lane = threadIdx.x & 63;
  size_t row = (size_t)blockIdx.x * 4 + w;
  const float* xr = x + row * 768;
  float4 v[3];
  float s = 0.f, sq = 0.f;
#pragma unroll
  for (int k = 0; k < 3; k++) {
    v[k] = *(const float4*)(xr + (k * 64 + lane) * 4);
    s += v[k].x + v[k].y + v[k].z + v[k].w;
    sq += v[k].x * v[k].x + v[k].y * v[k].y + v[k].z * v[k].z + v[k].w * v[k].w;
  }
#pragma unroll
  for (int off = 32; off >= 1; off >>= 1) {
    s += __shfl_xor(s, off);
    sq += __shfl_xor(sq, off);
  }
  float mean = s * (1.f / 768.f);
  float rstd = rsqrtf(sq * (1.f / 768.f) - mean * mean + 1e-5f);
#pragma unroll
  for (int k = 0; k < 3; k++) {
    int c = (k * 64 + lane) * 4;
    float4 gg = *(const float4*)(g + c);
    float4 bb = *(const float4*)(b + c);
    bf16x4 pk = {(bf16)((v[k].x - mean) * rstd * gg.x + bb.x),
                 (bf16)((v[k].y - mean) * rstd * gg.y + bb.y),
                 (bf16)((v[k].z - mean) * rstd * gg.z + bb.z),
                 (bf16)((v[k].w - mean) * rstd * gg.w + bb.w)};
    *(bf16x4*)(ob + row * 768 + c) = pk;
  }
}

// ------- ln2_reduce: t = p0+p1+b_o+x(resid f32); x2=t (bf16); h2 = LN(t) bf16 -
__global__ __launch_bounds__(256) void ln2_reduce_kernel(
    const bf16* __restrict__ p, const float* __restrict__ bo,
    const float* __restrict__ xres, const float* __restrict__ g,
    const float* __restrict__ b, bf16* __restrict__ x2,
    bf16* __restrict__ h2) {
  int w = threadIdx.x >> 6, lane = threadIdx.x & 63;
  size_t row = (size_t)blockIdx.x * 4 + w;
  const bf16* p0 = p + row * 768;
  const bf16* p1 = p0 + (size_t)M_TOK * 768;
  const float* xr = xres + row * 768;
  float4 v[3];
  float s = 0.f, sq = 0.f;
#pragma unroll
  for (int k = 0; k < 3; k++) {
    int c = (k * 64 + lane) * 4;
    bf16x4 a0 = *(const bf16x4*)(p0 + c);
    bf16x4 a1 = *(const bf16x4*)(p1 + c);
    float4 bb = *(const float4*)(bo + c);
    float4 rr = *(const float4*)(xr + c);
    v[k].x = (float)a0[0] + (float)a1[0] + bb.x + rr.x;
    v[k].y = (float)a0[1] + (float)a1[1] + bb.y + rr.y;
    v[k].z = (float)a0[2] + (float)a1[2] + bb.z + rr.z;
    v[k].w = (float)a0[3] + (float)a1[3] + bb.w + rr.w;
    bf16x4 xo = {(bf16)v[k].x, (bf16)v[k].y, (bf16)v[k].z, (bf16)v[k].w};
    *(bf16x4*)(x2 + row * 768 + c) = xo;
    s += v[k].x + v[k].y + v[k].z + v[k].w;
    sq += v[k].x * v[k].x + v[k].y * v[k].y + v[k].z * v[k].z + v[k].w * v[k].w;
  }
#pragma unroll
  for (int off = 32; off >= 1; off >>= 1) {
    s += __shfl_xor(s, off);
    sq += __shfl_xor(sq, off);
  }
  float mean = s * (1.f / 768.f);
  float rstd = rsqrtf(sq * (1.f / 768.f) - mean * mean + 1e-5f);
#pragma unroll
  for (int k = 0; k < 3; k++) {
    int c = (k * 64 + lane) * 4;
    float4 gg = *(const float4*)(g + c);
    float4 bb = *(const float4*)(b + c);
    bf16x4 pk = {(bf16)((v[k].x - mean) * rstd * gg.x + bb.x),
                 (bf16)((v[k].y - mean) * rstd * gg.y + bb.y),
                 (bf16)((v[k].z - mean) * rstd * gg.z + bb.z),
                 (bf16)((v[k].w - mean) * rstd * gg.w + bb.w)};
    *(bf16x4*)(h2 + row * 768 + c) = pk;
  }
}

// ------- ln3_reduce: t = gelu(p0+p1+b2)+x2(bf16); out = LN(t) f32 -------------
__global__ __launch_bounds__(256) void ln3_reduce_kernel(
    const bf16* __restrict__ p, const float* __restrict__ b2,
    const bf16* __restrict__ x2, const float* __restrict__ g,
    const float* __restrict__ b, float* __restrict__ out) {
  int w = threadIdx.x >> 6, lane = threadIdx.x & 63;
  size_t row = (size_t)blockIdx.x * 4 + w;
  const bf16* p0 = p + row * 768;
  const bf16* p1 = p0 + (size_t)M_TOK * 768;
  const bf16* xr = x2 + row * 768;
  float4 v[3];
  float s = 0.f, sq = 0.f;
#pragma unroll
  for (int k = 0; k < 3; k++) {
    int c = (k * 64 + lane) * 4;
    bf16x4 a0 = *(const bf16x4*)(p0 + c);
    bf16x4 a1 = *(const bf16x4*)(p1 + c);
    float4 bb = *(const float4*)(b2 + c);
    bf16x4 rr = *(const bf16x4*)(xr + c);
    v[k].x = gelu_f((float)a0[0] + (float)a1[0] + bb.x) + (float)rr[0];
    v[k].y = gelu_f((float)a0[1] + (float)a1[1] + bb.y) + (float)rr[1];
    v[k].z = gelu_f((float)a0[2] + (float)a1[2] + bb.z) + (float)rr[2];
    v[k].w = gelu_f((float)a0[3] + (float)a1[3] + bb.w) + (float)rr[3];
    s += v[k].x + v[k].y + v[k].z + v[k].w;
    sq += v[k].x * v[k].x + v[k].y * v[k].y + v[k].z * v[k].z + v[k].w * v[k].w;
  }
#pragma unroll
  for (int off = 32; off >= 1; off >>= 1) {
    s += __shfl_xor(s, off);
    sq += __shfl_xor(sq, off);
  }
  float mean = s * (1.f / 768.f);
  float rstd = rsqrtf(sq * (1.f / 768.f) - mean * mean + 1e-5f);
#pragma unroll
  for (int k = 0; k < 3; k++) {
    int c = (k * 64 + lane) * 4;
    float4 gg = *(const float4*)(g + c);
    float4 bb = *(const float4*)(b + c);
    float4 ov = {(v[k].x - mean) * rstd * gg.x + bb.x,
                 (v[k].y - mean) * rstd * gg.y + bb.y,
                 (v[k].z - mean) * rstd * gg.z + bb.z,
                 (v[k].w - mean) * rstd * gg.w + bb.w};
    *(float4*)(out + row * 768 + c) = ov;
  }
}

// ---------------- GEMM: C = A @ B^T, 128x128 (R5 body) + XCD supertiling ------
// ROUND-7: K-loop/staging byte-identical to R5 (best measured: 55.0 us W1,
// MfmaUtil 28.6, 0 bank conflicts). ONE change: block->tile assignment.
// R5's x(=m)-fastest dispatch gave every XCD a working set of ALL of A +
// several B panels -> the ~11 TB/s staging stream was served by L3, not L2
// (FETCH 34.4 MB vs 17.3 ideal). Remap (T1 mechanism, bijective):
//   id2 = y*gx + x ; xcd = id2 & 7 ; slot = id2 >> 3 ;
//   mt  = xcd*(gx/8) + slot % (gx/8) ; nt = slot / (gx/8)
// HW round-robins consecutive ids across XCDs -> XCD k owns the contiguous
// m-stripe [8k,8k+8) (A stripe 1.5 MB, L2-resident for the XCD's lifetime)
// and sweeps n with m fastest (each B tile L2-reused by 8 consecutive co-XCD
// blocks). Per-XCD beyond-L2 traffic ~75 MB -> ~6 MB. Split-K z-planes are
// gx*gy = 384 apart (== 0 mod 8) so the id<->XCD phase is preserved.
// Same tiles, same K order -> numerics unchanged.
template <int EPI, int LDA, int KTOT, int KSL, int NN>
__global__ __launch_bounds__(256, 3) void gemm128_kernel(
    const bf16* __restrict__ A, const bf16* __restrict__ Bf,
    const float* __restrict__ bias, bf16* __restrict__ outb,
    bf16* __restrict__ qo, bf16* __restrict__ ko, bf16* __restrict__ vto) {
  constexpr int KCg = KTOT / 32;   // B frag chunks per n16 row
  constexpr int NT = KSL / 32;     // K-tiles: 24 / 12 / 48 (all % 3 == 0)
  __shared__ __align__(16) bf16 smem[3][8192];  // per buf: A 8KB | B 8KB
  int tid = threadIdx.x;
  int w = tid >> 6, l = tid & 63;
  int qd = l >> 4, lr = l & 15;
  // ---- XCD-aware supertile remap (bijective; gx == 64) ----
  int id2 = blockIdx.y * gridDim.x + blockIdx.x;
  int xcd = id2 & 7;
  int slot = id2 >> 3;
  int Mg = gridDim.x >> 3;              // m-tiles per XCD stripe (8)
  int mt = xcd * Mg + (slot % Mg);
  int ntl = slot / Mg;
  int bm0 = mt * 128, bn0 = ntl * 128;
  int kb = blockIdx.z * KSL;
  int wm = (w >> 1) * 64, wn = (w & 1) * 64;
  int wnl = (w & 1) * 4;           // wave's first n16 frag

  // staging sources (per-lane; LDS dest wave-uniform + lane*16B linear)
  const bf16* pA = A + (size_t)(bm0 + w * 32 + (l >> 2)) * LDA + kb +
                   (((l & 3) ^ ((l >> 3) & 3)) * 8);
  const bf16* pB =
      Bf + ((size_t)((bn0 >> 4) + w * 2) * KCg + (kb >> 5)) * 512 + l * 8;

  auto STG = [&](int t, int b) {  // stage full 16KB tile t into buf b
    char* dA = (char*)smem[b] + w * 2048;
    char* dB = (char*)smem[b] + 8192 + w * 2048;
    gld_lds16(pA + t * 32, dA);
    gld_lds16(pA + t * 32 + (size_t)16 * LDA, dA + 1024);
    gld_lds16(pB + (size_t)t * 512, dB);
    gld_lds16(pB + (size_t)KCg * 512 + (size_t)t * 512, dB + 1024);
  };
  auto LDF = [&](int b, bf16x8* af, bf16x8* bv) {
    const bf16* Ab = smem[b];
    const bf16* Bb = smem[b] + 4096;
#pragma unroll
    for (int i = 0; i < 4; ++i) {
      int r = wm + i * 16 + lr;
      af[i] = *(const bf16x8*)(Ab + r * 32 + ((qd ^ ((lr >> 1) & 3)) * 8));
    }
#pragma unroll
    for (int j = 0; j < 4; ++j)
      bv[j] = *(const bf16x8*)(Bb + (wnl + j) * 512 + l * 8);
  };

  f32x4 acc[4][4] = {};

  // prologue: tiles 0,1 staged; drain tile 0 (oldest 4), keep tile 1 in flight
  STG(0, 0);
  STG(1, 1);
  asm volatile("s_waitcnt vmcnt(4)" ::: "memory");
  __builtin_amdgcn_sched_barrier(0);
  __builtin_amdgcn_s_barrier();

#pragma unroll 1
  for (int t3 = 0; t3 < NT; t3 += 3) {
#pragma unroll
    for (int u = 0; u < 3; ++u) {
      const int t = t3 + u;
      const bool st = (t + 2) < NT;
      // stage 2 ahead into the buffer freed at the end of iter t-1
      if (st) STG(t + 2, (u + 2) % 3);
      __builtin_amdgcn_sched_barrier(0);
      bf16x8 af[4], bv[4];
      LDF(u, af, bv);
      asm volatile("s_waitcnt lgkmcnt(0)" ::: "memory");
      __builtin_amdgcn_sched_barrier(0);
      __builtin_amdgcn_s_setprio(1);
#pragma unroll
      for (int i = 0; i < 4; ++i)
#pragma unroll
        for (int j = 0; j < 4; ++j)
          acc[i][j] = __builtin_amdgcn_mfma_f32_16x16x32_bf16(
              af[i], bv[j], acc[i][j], 0, 0, 0);
      __builtin_amdgcn_s_setprio(0);
      if (t + 1 < NT) {
        // counted: tile t+1 landed; only tile t+2's 4 loads may stay in flight
        if (st) asm volatile("s_waitcnt vmcnt(4)" ::: "memory");
        else    asm volatile("s_waitcnt vmcnt(0)" ::: "memory");
        __builtin_amdgcn_sched_barrier(0);
        __builtin_amdgcn_s_barrier();
      }
    }
  }

  // ---- epilogue ----
  bf16* outbs = (EPI == 5) ? outb + (size_t)blockIdx.z * M_TOK * NN : outb;

#pragma unroll
  for (int i = 0; i < 4; i++) {
#pragma unroll
    for (int j = 0; j < 4; j++) {
      if (EPI == 4) {
        // fused qkv split (NN==2304). 16-col tiles never straddle head bounds.
        int colt = bn0 + wn + j * 16;
        int which = colt / 768;
        int rem = colt - which * 768;
        int h = rem / 96;
        int dhb = rem - h * 96;
        int row0 = bm0 + wm + i * 16 + qd * 4;
        int b = row0 >> 10, n0 = row0 & 1023;
        int bh = b * 8 + h;
        if (which == 2) {
          bf16x4 pk = {(bf16)acc[i][j][0], (bf16)acc[i][j][1],
                       (bf16)acc[i][j][2], (bf16)acc[i][j][3]};
          *(bf16x4*)(vto + ((size_t)(bh * 96 + dhb + lr)) * 1024 + n0) = pk;
        } else if (which == 0) {
          // q pre-scaled by 1/sqrt(dh) so attention skips the S-scale
#pragma unroll
          for (int r = 0; r < 4; r++)
            qo[((size_t)bh * 1024 + n0 + r) * 96 + dhb + lr] =
                (bf16)(acc[i][j][r] * SCALE_);
        } else {
#pragma unroll
          for (int r = 0; r < 4; r++)
            ko[((size_t)bh * 1024 + n0 + r) * 96 + dhb + lr] =
                (bf16)acc[i][j][r];
        }
      } else {
#pragma unroll
        for (int r = 0; r < 4; r++) {
          int row = bm0 + wm + i * 16 + qd * 4 + r;
          int col = bn0 + wn + j * 16 + lr;
          size_t o = (size_t)row * NN + col;
          float v = acc[i][j][r];
          if (EPI == 2) {
            outbs[o] = (bf16)gelu_f(v + bias[col]);
          } else {  // EPI == 5
            outbs[o] = (bf16)v;
          }
        }
      }
    }
  }
}

// ---------------- fused attention, 128 q-rows/block, 64-key tiles -------------
__global__ __launch_bounds__(256) void attn_kernel(
    const bf16* __restrict__ qb, const bf16* __restrict__ kb,
    const bf16* __restrict__ vtb, bf16* __restrict__ operm) {
  __shared__ __align__(16) bf16 Ks[2][64 * 104];   // [key][dh], pad 104
  __shared__ __align__(16) bf16 Vs[2][96 * 72];    // [dh][key], pad 72
  __shared__ __align__(16) bf16 Ps[128 * 72];      // [qrow][key], pad 72
  int t = threadIdx.x;
  int w = t >> 6, lane = t & 63;
  int qd = lane >> 4, lr = lane & 15;
  int bh = blockIdx.x, nt0 = blockIdx.y * 128;
  int bq = bh >> 3, hh = bh & 7;

  const bf16* kgb = kb + (size_t)bh * 1024 * 96;
  const bf16* vgb = vtb + (size_t)bh * 96 * 1024;

  bf16x8 kreg[3], vreg[3];
#pragma unroll
  for (int it = 0; it < 3; it++) {
    int idx = it * 256 + t;
    kreg[it] = *(const bf16x8*)(kgb + (idx / 12) * 96 + (idx % 12) * 8);
    vreg[it] = *(const bf16x8*)(vgb + (size_t)(idx >> 3) * 1024 + (idx & 7) * 8);
  }

  const bf16* qg = qb + ((size_t)bh * 1024 + nt0 + w * 32) * 96;
  bf16x8 afq[2][3];
#pragma unroll
  for (int i = 0; i < 2; i++)
#pragma unroll
    for (int ks = 0; ks < 3; ks++)
      afq[i][ks] = *(const bf16x8*)(qg + (i * 16 + lr) * 96 + ks * 32 + qd * 8);

  f32x4 oacc[2][6] = {};
  float lst[2][4] = {};

  int cur = 0;
  for (int kt = 0; kt < 16; kt++) {
#pragma unroll
    for (int it = 0; it < 3; it++) {
      int idx = it * 256 + t;
      *(bf16x8*)&Ks[cur][(idx / 12) * 104 + (idx % 12) * 8] = kreg[it];
      *(bf16x8*)&Vs[cur][(idx >> 3) * 72 + (idx & 7) * 8] = vreg[it];
    }
    if (kt < 15) {
      const bf16* kg = kgb + (size_t)(kt + 1) * 64 * 96;
      const bf16* vg = vgb + (kt + 1) * 64;
#pragma unroll
      for (int it = 0; it < 3; it++) {
        int idx = it * 256 + t;
        kreg[it] = *(const bf16x8*)(kg + (idx / 12) * 96 + (idx % 12) * 8);
        vreg[it] =
            *(const bf16x8*)(vg + (size_t)(idx >> 3) * 1024 + (idx & 7) * 8);
      }
    }
    __syncthreads();

    f32x4 sacc[2][4] = {};
#pragma unroll
    for (int ks = 0; ks < 3; ks++) {
      bf16x8 bk[4];
#pragma unroll
      for (int jn = 0; jn < 4; jn++)
        bk[jn] =
            *(const bf16x8*)&Ks[cur][(jn * 16 + lr) * 104 + ks * 32 + qd * 8];
#pragma unroll
      for (int i = 0; i < 2; i++)
#pragma unroll
        for (int jn = 0; jn < 4; jn++)
          sacc[i][jn] = __builtin_amdgcn_mfma_f32_16x16x32_bf16(
              afq[i][ks], bk[jn], sacc[i][jn], 0, 0, 0);
    }

#pragma unroll
    for (int i = 0; i < 2; i++)
#pragma unroll
      for (int jn = 0; jn < 4; jn++)
#pragma unroll
        for (int r = 0; r < 4; r++) {
          float p = __expf(sacc[i][jn][r]);
          lst[i][r] += p;
          Ps[(w * 32 + i * 16 + qd * 4 + r) * 72 + jn * 16 + lr] = (bf16)p;
        }

#pragma unroll
    for (int ks = 0; ks < 2; ks++) {
      bf16x8 ap[2];
#pragma unroll
      for (int i = 0; i < 2; i++)
        ap[i] =
            *(const bf16x8*)&Ps[(w * 32 + i * 16 + lr) * 72 + ks * 32 + qd * 8];
#pragma unroll
      for (int jn = 0; jn < 6; jn++) {
        bf16x8 bv =
            *(const bf16x8*)&Vs[cur][(jn * 16 + lr) * 72 + ks * 32 + qd * 8];
#pragma unroll
        for (int i = 0; i < 2; i++)
          oacc[i][jn] = __builtin_amdgcn_mfma_f32_16x16x32_bf16(
              ap[i], bv, oacc[i][jn], 0, 0, 0);
      }
    }
    cur ^= 1;
  }

#pragma unroll
  for (int i = 0; i < 2; i++)
#pragma unroll
    for (int r = 0; r < 4; r++) {
#pragma unroll
      for (int off = 1; off < 16; off <<= 1)
        lst[i][r] += __shfl_xor(lst[i][r], off);
    }

#pragma unroll
  for (int i = 0; i < 2; i++) {
#pragma unroll
    for (int r = 0; r < 4; r++) {
      float inv = 1.0f / lst[i][r];
      int n = nt0 + w * 32 + i * 16 + qd * 4 + r;
      size_t rowo = (size_t)bq * 1024 + hh * 128 + (n >> 3);
      int colb = 96 * (n & 7);
#pragma unroll
      for (int jn = 0; jn < 6; jn++)
        operm[rowo * 768 + colb + jn * 16 + lr] =
            (bf16)(oacc[i][jn][r] * inv);
    }
  }
}

// ------------------------------------------------------------------------------
extern "C" void kernel_launch(void* const* d_in, const int* in_sizes, int n_in,
                              void* d_out, int out_size, void* d_ws,
                              size_t ws_size, hipStream_t stream) {
  const float* x = (const float*)d_in[0];
  const float* w_qkv = (const float*)d_in[1];
  const float* w_o = (const float*)d_in[2];
  const float* b_o = (const float*)d_in[3];
  const float* w1 = (const float*)d_in[4];
  const float* b1 = (const float*)d_in[5];
  const float* w2 = (const float*)d_in[6];
  const float* b2 = (const float*)d_in[7];
  const float* g1 = (const float*)d_in[8];
  const float* be1 = (const float*)d_in[9];
  const float* gm = (const float*)d_in[10];
  const float* bm = (const float*)d_in[11];
  const float* g3 = (const float*)d_in[12];
  const float* be3 = (const float*)d_in[13];

  char* ws = (char*)d_ws;
  size_t off = 0;
  auto alloc = [&](size_t bytes) {
    char* p = ws + off;
    off += (bytes + 255) & ~(size_t)255;
    return p;
  };
  const size_t SZ_TOK_BF = (size_t)M_TOK * 768 * 2;   // 12.58 MB
  bf16* fqkv = (bf16*)alloc((size_t)2304 * 768 * 2);
  bf16* fwo = (bf16*)alloc((size_t)768 * 768 * 2);
  bf16* fw1 = (bf16*)alloc((size_t)3072 * 768 * 2);
  bf16* fw2 = (bf16*)alloc((size_t)768 * 3072 * 2);
  bf16* hA = (bf16*)alloc(SZ_TOK_BF);   // LN1 out; then operm; then h2
  bf16* qb = (bf16*)alloc(SZ_TOK_BF);
  bf16* kbuf = (bf16*)alloc(SZ_TOK_BF);
  bf16* vtb = (bf16*)alloc(SZ_TOK_BF);
  bf16* x2 = (bf16*)alloc(SZ_TOK_BF);
  char* G = alloc((size_t)M_TOK * 3072 * 2);
  bf16* operm = hA;
  bf16* h2 = hA;
  bf16* pWo = (bf16*)G;
  bf16* a1 = (bf16*)G;
  bf16* pW2 = hA;  // spans hA+qb (2 x 12.58 MB), live after a1's last read

  make_frags_kernel<<<3456, 256, 0, stream>>>(w_qkv, w_o, w1, w2, fqkv, fwo,
                                              fw1, fw2);

  ln_kernel<<<M_TOK / 4, 256, 0, stream>>>(x, g1, be1, hA);

  // QKV GEMM with fused head-split epilogue (q pre-scaled by 1/sqrt(dh))
  gemm128_kernel<4, 768, 768, 768, 2304><<<dim3(64, 18), 256, 0, stream>>>(
      hA, fqkv, nullptr, nullptr, qb, kbuf, vtb);

  attn_kernel<<<dim3(64, 8), 256, 0, stream>>>(qb, kbuf, vtb, operm);

  // Wo GEMM, split-K=2 (slices of 384) -> bf16 partials in G
  gemm128_kernel<5, 768, 768, 384, 768><<<dim3(64, 6, 2), 256, 0, stream>>>(
      operm, fwo, nullptr, pWo, nullptr, nullptr, nullptr);

  ln2_reduce_kernel<<<M_TOK / 4, 256, 0, stream>>>(pWo, b_o, x, gm, bm, x2, h2);

  // W1 GEMM: bias + GELU -> bf16 a1
  gemm128_kernel<2, 768, 768, 768, 3072><<<dim3(64, 24), 256, 0, stream>>>(
      h2, fw1, b1, a1, nullptr, nullptr, nullptr);

  // W2 GEMM, split-K=2 (slices of 1536) -> bf16 partials spanning hA+qb
  gemm128_kernel<5, 3072, 3072, 1536, 768><<<dim3(64, 6, 2), 256, 0, stream>>>(
      a1, fw2, nullptr, pW2, nullptr, nullptr, nullptr);

  ln3_reduce_kernel<<<M_TOK / 4, 256, 0, stream>>>(pW2, b2, x2, g3, be3,
                                                   (float*)d_out);
}